// Round 21
// baseline (603.905 us; speedup 1.0000x reference)
//
#include <hip/hip_runtime.h>

#define DEVFN __device__ __forceinline__

constexpr int GN = 100000, GE = 3200000;
constexpr int GE1 = GE + GN;          // 3,300,000
constexpr int GE2 = GE1 + GN;         // 3,400,000
constexpr int GEMB = 128, GHID = 16, GOUT = 32;
constexpr float GNEG = 0.2f;
constexpr float GEA2 = 100000.f / 3300000.f;   // mean(alpha1) = N/E1 exactly

constexpr long long G0 = (long long)GN * GOUT;   //  3,200,000  (out end)
constexpr long long G1 = G0 + 2LL * GE2;         // 10,000,000  (ei2 end; a2 follows)

constexpr unsigned CHUNK = 400000;    // pse slots per XCD-chunk

// ---- ws layout (floats), 56.8 MB ----
constexpr size_t W_ESC  = 0;          // GE2: alpha slots (self at GE+u, GE1+u)
constexpr size_t W_LG   = 3400000;    // GE2: logits (no aliasing in hot loops)
constexpr size_t W_XL1H = 6800000;    // N*HID bf16
constexpr size_t W_XR1  = 7600000;    // N*HID f32
constexpr size_t W_XL2H = 9200000;    // N*OUT bf16
constexpr size_t W_XR2  = 10800000;   // N*OUT f32
constexpr size_t W_RP   = 14000000;   // rowptr N+1 (int)
constexpr size_t W_CNT  = 14100004;   // cnt N (int)
constexpr size_t W_BS   = 14200004;   // scan block sums (256)
constexpr size_t W_SEA  = 14200260;
constexpr size_t W_WPI  = 14200261;
constexpr size_t W_END  = 14200264;

DEVFN int gidx(const int* __restrict__ ei, long long i, int wpi) {
    return ei[(size_t)i * (size_t)wpi];
}
DEVFN unsigned short f2b(float f) {               // f32 -> bf16 RNE
    unsigned u = __float_as_uint(f);
    unsigned r = ((u >> 16) & 1u) + 0x7fffu;
    return (unsigned short)((u + r) >> 16);
}
DEVFN float b2fl(unsigned u) { return __uint_as_float(u << 16); }
DEVFN float b2fh(unsigned u) { return __uint_as_float(u & 0xffff0000u); }

__global__ void gl_sentinel(float* outb) {        // ws too small -> Output 2 ~ 3840
    if (threadIdx.x == 0 && blockIdx.x == 0) outb[G1] = 3840.0f;
}

__global__ void gl_detect(const int* __restrict__ ei, int* flag) {
    int t = threadIdx.x;
    int v = ei[2 * t + 1];
    unsigned long long nz = __ballot(v != 0);
    if (t == 0) *flag = (nz == 0ull) ? 2 : 1;
}

__global__ void gl_sum(const float* __restrict__ p, int n, float* __restrict__ out) {
    float s = 0.f;
    for (int i = blockIdx.x * blockDim.x + threadIdx.x; i < n; i += gridDim.x * blockDim.x)
        s += p[i];
    #pragma unroll
    for (int o = 32; o > 0; o >>= 1) s += __shfl_down(s, o);
    __shared__ float ls[4];
    if ((threadIdx.x & 63) == 0) ls[threadIdx.x >> 6] = s;
    __syncthreads();
    if (threadIdx.x == 0) atomicAdd(out, ls[0] + ls[1] + ls[2] + ls[3]);
}

__global__ __launch_bounds__(256) void gl_projA(const float* __restrict__ x,
        const float* __restrict__ Wl, const float* __restrict__ Wr,
        unsigned short* __restrict__ xlh, float* __restrict__ xr) {
    __shared__ float sWl[GEMB * GHID], sWr[GEMB * GHID], sx[16 * GEMB];
    for (int i = threadIdx.x; i < GEMB * GHID; i += 256) { sWl[i] = Wl[i]; sWr[i] = Wr[i]; }
    int base = blockIdx.x * 16;
    for (int i = threadIdx.x; i < 16 * GEMB; i += 256) sx[i] = x[(size_t)base * GEMB + i];
    __syncthreads();
    int ln = threadIdx.x >> 4, ch = threadIdx.x & 15;
    float al = 0.f, ar = 0.f;
    #pragma unroll 8
    for (int k = 0; k < GEMB; ++k) {
        float xv = sx[ln * GEMB + k];
        al = fmaf(xv, sWl[k * GHID + ch], al);
        ar = fmaf(xv, sWr[k * GHID + ch], ar);
    }
    xlh[(size_t)(base + ln) * GHID + ch] = f2b(al);
    xr[(size_t)(base + ln) * GHID + ch] = ar;
}

__global__ __launch_bounds__(256) void gl_projB(const float* __restrict__ h,
        const float* __restrict__ Wl, const float* __restrict__ Wr,
        unsigned short* __restrict__ xlh, float* __restrict__ xr) {
    __shared__ float sWl[GHID * GOUT], sWr[GHID * GOUT], sx[8 * GHID];
    for (int i = threadIdx.x; i < GHID * GOUT; i += 256) { sWl[i] = Wl[i]; sWr[i] = Wr[i]; }
    int base = blockIdx.x * 8;
    for (int i = threadIdx.x; i < 8 * GHID; i += 256) sx[i] = h[(size_t)base * GHID + i];
    __syncthreads();
    int ln = threadIdx.x >> 5, ch = threadIdx.x & 31;
    float al = 0.f, ar = 0.f;
    #pragma unroll
    for (int k = 0; k < GHID; ++k) {
        float xv = sx[ln * GHID + k];
        al = fmaf(xv, sWl[k * GOUT + ch], al);
        ar = fmaf(xv, sWr[k * GOUT + ch], ar);
    }
    xlh[(size_t)(base + ln) * GOUT + ch] = f2b(al);
    xr[(size_t)(base + ln) * GOUT + ch] = ar;
}

// ---- hist: count per dst, store per-edge local rank (into a2 region) ----
__global__ void gl_hist(const int* __restrict__ ei, const int* __restrict__ wpip,
                        int* __restrict__ cnt, int* __restrict__ rank) {
    int e = blockIdx.x * blockDim.x + threadIdx.x;
    if (e >= GE) return;
    int wpi = *wpip;
    int dst = gidx(ei, (long long)GE + e, wpi);
    rank[e] = atomicAdd(&cnt[dst], 1);
}

__global__ __launch_bounds__(1024) void gl_scan1(const int* __restrict__ cnt,
                                                 int* __restrict__ rp, int* __restrict__ bs) {
    __shared__ int s[1024];
    int t = threadIdx.x, u = blockIdx.x * 1024 + t;
    s[t] = (u < GN) ? cnt[u] : 0;
    __syncthreads();
    for (int off = 1; off < 1024; off <<= 1) {
        int a = (t >= off) ? s[t - off] : 0;
        __syncthreads();
        s[t] += a;
        __syncthreads();
    }
    if (u < GN) rp[u + 1] = s[t];
    if (t == 1023) bs[blockIdx.x] = s[1023];
}
__global__ void gl_scan2(int* __restrict__ bs, int nb) {
    __shared__ int s[128];
    int t = threadIdx.x;
    s[t] = (t < nb) ? bs[t] : 0;
    __syncthreads();
    for (int off = 1; off < 128; off <<= 1) {
        int a = (t >= off) ? s[t - off] : 0;
        __syncthreads();
        s[t] += a;
        __syncthreads();
    }
    if (t < nb) bs[t] = (t == 0) ? 0 : s[t - 1];
}
__global__ void gl_scan3(int* __restrict__ rp, const int* __restrict__ bs) {
    int u = blockIdx.x * blockDim.x + threadIdx.x;
    if (u < GN) rp[u + 1] += bs[u >> 10];
    if (u == 0) rp[0] = 0;
}

// ---- scatter: chunk-per-XCD; slot computed inline (rp is L2-resident) ----
__global__ __launch_bounds__(256) void gl_scatter(const int* __restrict__ ei,
        const int* __restrict__ wpip, const float* __restrict__ eattr,
        const int* __restrict__ rank, const int* __restrict__ rp,
        int2* __restrict__ pse) {
    int wpi = *wpip;
    unsigned ck = blockIdx.x & 7;
    int stride = (gridDim.x >> 3) * 256;
    for (int e = (blockIdx.x >> 3) * 256 + threadIdx.x; e < GE; e += stride) {
        int dst = gidx(ei, (long long)GE + e, wpi);
        int slot = rp[dst] + rank[e];
        if ((unsigned)slot / CHUNK == ck) {
            int src = gidx(ei, e, wpi);
            pse[slot] = make_int2(src, __float_as_int(eattr[e]));
        }
    }
}

// ------- fused layer 1: 4 lanes/edge, depth-2 gather pipeline (HID=16) -------
__global__ __launch_bounds__(256) void gl_L1(const int* __restrict__ rp,
        const int2* __restrict__ pse, const float* __restrict__ sea,
        const unsigned short* __restrict__ xlh, const float* __restrict__ xr,
        const float* __restrict__ We, const float* __restrict__ att,
        const float* __restrict__ b1, float* __restrict__ esc,
        float* __restrict__ lg, float* __restrict__ h1) {
    int u = blockIdx.x * 4 + (threadIdx.x >> 6);
    int lane = threadIdx.x & 63, sg = lane >> 2, ln4 = lane & 3;
    int beg = rp[u], end = rp[u + 1];
    float4 we = *(const float4*)(We + ln4 * 4);
    float4 at = *(const float4*)(att + ln4 * 4);
    float4 xru = *(const float4*)(xr + (size_t)u * GHID + ln4 * 4);
    float mx = -3.0e38f, pd = 0.f;
    float4 acc = make_float4(0.f, 0.f, 0.f, 0.f);
    int i = beg + sg;
    int2 p = (i < end) ? pse[i] : make_int2(0, 0);
    uint2 h = (i < end) ? *(const uint2*)(xlh + (size_t)p.x * GHID + ln4 * 4)
                        : make_uint2(0, 0);
    for (; i < end; i += 16) {
        int inx = i + 16;
        int2 pn = (inx < end) ? pse[inx] : make_int2(0, 0);
        uint2 hn = (inx < end) ? *(const uint2*)(xlh + (size_t)pn.x * GHID + ln4 * 4)
                               : make_uint2(0, 0);
        float ea = __int_as_float(p.y);
        float x0 = b2fl(h.x), x1 = b2fh(h.x), x2 = b2fl(h.y), x3 = b2fh(h.y);
        float v, s = 0.f;
        v = x0 + xru.x + ea * we.x; v = v > 0.f ? v : GNEG * v; s = fmaf(v, at.x, s);
        v = x1 + xru.y + ea * we.y; v = v > 0.f ? v : GNEG * v; s = fmaf(v, at.y, s);
        v = x2 + xru.z + ea * we.z; v = v > 0.f ? v : GNEG * v; s = fmaf(v, at.z, s);
        v = x3 + xru.w + ea * we.w; v = v > 0.f ? v : GNEG * v; s = fmaf(v, at.w, s);
        s += __shfl_xor(s, 1); s += __shfl_xor(s, 2);
        if (ln4 == 0) lg[i] = s;
        float nm = fmaxf(mx, s);
        float sc = __expf(mx - nm), pp = __expf(s - nm);
        pd = pd * sc + pp;
        acc.x = acc.x * sc + pp * x0; acc.y = acc.y * sc + pp * x1;
        acc.z = acc.z * sc + pp * x2; acc.w = acc.w * sc + pp * x3;
        mx = nm;
        p = pn; h = hn;
    }
    float lgself = 0.f;
    if (sg == 0) {                                  // self-loop (ea = mean(edge_attr))
        uint2 hs = *(const uint2*)(xlh + (size_t)u * GHID + ln4 * 4);
        float ea = sea[0] * (1.f / (float)GE);
        float x0 = b2fl(hs.x), x1 = b2fh(hs.x), x2 = b2fl(hs.y), x3 = b2fh(hs.y);
        float v, s = 0.f;
        v = x0 + xru.x + ea * we.x; v = v > 0.f ? v : GNEG * v; s = fmaf(v, at.x, s);
        v = x1 + xru.y + ea * we.y; v = v > 0.f ? v : GNEG * v; s = fmaf(v, at.y, s);
        v = x2 + xru.z + ea * we.z; v = v > 0.f ? v : GNEG * v; s = fmaf(v, at.z, s);
        v = x3 + xru.w + ea * we.w; v = v > 0.f ? v : GNEG * v; s = fmaf(v, at.w, s);
        s += __shfl_xor(s, 1); s += __shfl_xor(s, 2);
        lgself = s;
        float nm = fmaxf(mx, s);
        float sc = __expf(mx - nm), pp = __expf(s - nm);
        pd = pd * sc + pp;
        acc.x = acc.x * sc + pp * x0; acc.y = acc.y * sc + pp * x1;
        acc.z = acc.z * sc + pp * x2; acc.w = acc.w * sc + pp * x3;
        mx = nm;
    }
    #pragma unroll
    for (int o = 4; o <= 32; o <<= 1) {             // merge 16 subgroups
        float mo = __shfl_xor(mx, o), po = __shfl_xor(pd, o);
        float a0 = __shfl_xor(acc.x, o), a1 = __shfl_xor(acc.y, o);
        float a2 = __shfl_xor(acc.z, o), a3 = __shfl_xor(acc.w, o);
        float nm = fmaxf(mx, mo);
        float sa = __expf(mx - nm), sb = __expf(mo - nm);
        pd = pd * sa + po * sb;
        acc.x = acc.x * sa + a0 * sb; acc.y = acc.y * sa + a1 * sb;
        acc.z = acc.z * sa + a2 * sb; acc.w = acc.w * sa + a3 * sb;
        mx = nm;
    }
    float dinv = 1.f / pd;
    __threadfence_block();
    for (int j = beg + lane; j < end; j += 64)      // alpha pass (coalesced)
        esc[j] = __expf(lg[j] - mx) * dinv;
    if (lane == 0) esc[GE + u] = __expf(lgself - mx) * dinv;
    if (lane < 4) {
        float4 b = *(const float4*)(b1 + lane * 4);
        float4 o;
        o.x = acc.x * dinv + b.x; o.y = acc.y * dinv + b.y;
        o.z = acc.z * dinv + b.z; o.w = acc.w * dinv + b.w;
        o.x = o.x > 0.f ? o.x : 0.f; o.y = o.y > 0.f ? o.y : 0.f;
        o.z = o.z > 0.f ? o.z : 0.f; o.w = o.w > 0.f ? o.w : 0.f;
        *(float4*)(h1 + (size_t)u * GHID + lane * 4) = o;   // fused bias+relu
    }
}

// ------- fused layer 2: 8 lanes/edge, depth-2 gather pipeline (OUT=32) -------
__global__ __launch_bounds__(256) void gl_L2(const int* __restrict__ rp,
        const int2* __restrict__ pse,
        const unsigned short* __restrict__ xlh, const float* __restrict__ xr,
        const float* __restrict__ We, const float* __restrict__ att,
        const float* __restrict__ b2, float* __restrict__ esc,
        float* __restrict__ lg, float* __restrict__ out0) {
    int u = blockIdx.x * 4 + (threadIdx.x >> 6);
    int lane = threadIdx.x & 63, sg = lane >> 3, ln8 = lane & 7;
    int beg = rp[u], end = rp[u + 1];
    float4 we = *(const float4*)(We + ln8 * 4);
    float4 at = *(const float4*)(att + ln8 * 4);
    float4 xru = *(const float4*)(xr + (size_t)u * GOUT + ln8 * 4);
    float mx = -3.0e38f, pd = 0.f;
    float4 acc = make_float4(0.f, 0.f, 0.f, 0.f);
    int i = beg + sg;
    int2 p = (i < end) ? pse[i] : make_int2(0, 0);
    float ea = (i < end) ? esc[i] : 0.f;
    uint2 h = (i < end) ? *(const uint2*)(xlh + (size_t)p.x * GOUT + ln8 * 4)
                        : make_uint2(0, 0);
    for (; i < end; i += 8) {
        int inx = i + 8;
        int2 pn = (inx < end) ? pse[inx] : make_int2(0, 0);
        float ean = (inx < end) ? esc[inx] : 0.f;
        uint2 hn = (inx < end) ? *(const uint2*)(xlh + (size_t)pn.x * GOUT + ln8 * 4)
                               : make_uint2(0, 0);
        float x0 = b2fl(h.x), x1 = b2fh(h.x), x2 = b2fl(h.y), x3 = b2fh(h.y);
        float v, s = 0.f;
        v = x0 + xru.x + ea * we.x; v = v > 0.f ? v : GNEG * v; s = fmaf(v, at.x, s);
        v = x1 + xru.y + ea * we.y; v = v > 0.f ? v : GNEG * v; s = fmaf(v, at.y, s);
        v = x2 + xru.z + ea * we.z; v = v > 0.f ? v : GNEG * v; s = fmaf(v, at.z, s);
        v = x3 + xru.w + ea * we.w; v = v > 0.f ? v : GNEG * v; s = fmaf(v, at.w, s);
        s += __shfl_xor(s, 1); s += __shfl_xor(s, 2); s += __shfl_xor(s, 4);
        if (ln8 == 0) lg[i] = s;
        float nm = fmaxf(mx, s);
        float sc = __expf(mx - nm), pp = __expf(s - nm);
        pd = pd * sc + pp;
        acc.x = acc.x * sc + pp * x0; acc.y = acc.y * sc + pp * x1;
        acc.z = acc.z * sc + pp * x2; acc.w = acc.w * sc + pp * x3;
        mx = nm;
        p = pn; ea = ean; h = hn;
    }
    float lgs = 0.f;
    if (sg < 2) {   // two self-loops: sg0 -> ea=alpha1_self, sg1 -> ea=N/E1
        float eas = (sg == 0) ? esc[GE + u] : GEA2;
        uint2 hs = *(const uint2*)(xlh + (size_t)u * GOUT + ln8 * 4);
        float x0 = b2fl(hs.x), x1 = b2fh(hs.x), x2 = b2fl(hs.y), x3 = b2fh(hs.y);
        float v, s = 0.f;
        v = x0 + xru.x + eas * we.x; v = v > 0.f ? v : GNEG * v; s = fmaf(v, at.x, s);
        v = x1 + xru.y + eas * we.y; v = v > 0.f ? v : GNEG * v; s = fmaf(v, at.y, s);
        v = x2 + xru.z + eas * we.z; v = v > 0.f ? v : GNEG * v; s = fmaf(v, at.z, s);
        v = x3 + xru.w + eas * we.w; v = v > 0.f ? v : GNEG * v; s = fmaf(v, at.w, s);
        s += __shfl_xor(s, 1); s += __shfl_xor(s, 2); s += __shfl_xor(s, 4);
        lgs = s;
        float nm = fmaxf(mx, s);
        float sc = __expf(mx - nm), pp = __expf(s - nm);
        pd = pd * sc + pp;
        acc.x = acc.x * sc + pp * x0; acc.y = acc.y * sc + pp * x1;
        acc.z = acc.z * sc + pp * x2; acc.w = acc.w * sc + pp * x3;
        mx = nm;
    }
    #pragma unroll
    for (int o = 8; o <= 32; o <<= 1) {             // merge 8 subgroups
        float mo = __shfl_xor(mx, o), po = __shfl_xor(pd, o);
        float a0 = __shfl_xor(acc.x, o), a1 = __shfl_xor(acc.y, o);
        float a2 = __shfl_xor(acc.z, o), a3 = __shfl_xor(acc.w, o);
        float nm = fmaxf(mx, mo);
        float sa = __expf(mx - nm), sb = __expf(mo - nm);
        pd = pd * sa + po * sb;
        acc.x = acc.x * sa + a0 * sb; acc.y = acc.y * sa + a1 * sb;
        acc.z = acc.z * sa + a2 * sb; acc.w = acc.w * sa + a3 * sb;
        mx = nm;
    }
    float dinv = 1.f / pd;
    __threadfence_block();
    for (int j = beg + lane; j < end; j += 64)      // alpha2 pass (coalesced)
        esc[j] = __expf(lg[j] - mx) * dinv;
    if (lane == 0) esc[GE + u]  = __expf(lgs - mx) * dinv;
    if (lane == 8) esc[GE1 + u] = __expf(lgs - mx) * dinv;
    if (lane < 8) {
        float4 b = *(const float4*)(b2 + lane * 4);
        float4 o;
        o.x = acc.x * dinv + b.x; o.y = acc.y * dinv + b.y;
        o.z = acc.z * dinv + b.z; o.w = acc.w * dinv + b.w;
        *(float4*)(out0 + (size_t)u * GOUT + lane * 4) = o;
    }
}

// fused epilogue: ei2 (2 floats) + a2 (1 float) per index; slot = rp[dst]+rank[c].
// rank[c] lives at outb[G1+c] and is read before this thread overwrites it.
__global__ void gl_ep(const int* __restrict__ ei, const int* __restrict__ wpip,
                      const int* __restrict__ rank, const int* __restrict__ rp,
                      const float* __restrict__ esc, float* __restrict__ outb) {
    int c = blockIdx.x * blockDim.x + threadIdx.x;
    if (c >= GE2) return;
    int wpi = *wpip;
    int s, dd;
    float av;
    if (c < GE) {
        s = gidx(ei, c, wpi);
        dd = gidx(ei, (long long)GE + c, wpi);
        av = esc[rp[dd] + rank[c]];
    } else if (c < GE1) {
        s = dd = c - GE;
        av = esc[c];
    } else {
        s = dd = c - GE1;
        av = esc[c];
    }
    outb[G0 + c]       = (float)s;
    outb[G0 + GE2 + c] = (float)dd;
    outb[G1 + c]       = av;
}

extern "C" void kernel_launch(void* const* d_in, const int* in_sizes, int n_in,
                              void* d_out, int out_size, void* d_ws, size_t ws_size,
                              hipStream_t stream) {
    const float* x     = (const float*)d_in[0];
    const int*   ei    = (const int*)d_in[1];
    const float* eattr = (const float*)d_in[2];
    const float* W1l   = (const float*)d_in[3];
    const float* W1r   = (const float*)d_in[4];
    const float* W1e   = (const float*)d_in[5];
    const float* att1  = (const float*)d_in[6];
    const float* b1    = (const float*)d_in[7];
    const float* W2l   = (const float*)d_in[8];
    const float* W2r   = (const float*)d_in[9];
    const float* W2e   = (const float*)d_in[10];
    const float* att2  = (const float*)d_in[11];
    const float* b2    = (const float*)d_in[12];
    float* outf = (float*)d_out;

    float* ws = (float*)d_ws;
    if (W_END * sizeof(float) > ws_size) {          // 56.8 MB needed
        gl_sentinel<<<1, 64, 0, stream>>>(outf);
        return;
    }

    float*          esc  = ws + W_ESC;
    float*          lg   = ws + W_LG;
    unsigned short* xl1h = (unsigned short*)(ws + W_XL1H);
    float*          xr1  = ws + W_XR1;
    unsigned short* xl2h = (unsigned short*)(ws + W_XL2H);
    float*          xr2  = ws + W_XR2;
    int*            rp   = (int*)(ws + W_RP);
    int*            cnt  = (int*)(ws + W_CNT);
    int*            bs   = (int*)(ws + W_BS);
    float*          sea  = ws + W_SEA;
    int*            wpi  = (int*)(ws + W_WPI);

    // d_out scratch (strictly sequential reuse):
    //   pse : [G0, G0+6.4M) = ei2 region — killed by gl_ep.
    //   rank: [G1, G1+GE)   = a2 region  — read-then-overwritten by gl_ep.
    int2*  pse  = (int2*)(outf + G0);
    int*   rank = (int*)(outf + G1);
    float* h1   = outf;                             // chunk0, killed by L2's out0

    hipMemsetAsync(cnt, 0, GN * sizeof(int), stream);
    hipMemsetAsync(sea, 0, 2 * sizeof(float), stream);

    gl_detect<<<1, 64, 0, stream>>>(ei, wpi);
    gl_sum<<<1024, 256, 0, stream>>>(eattr, GE, sea);
    gl_projA<<<GN / 16, 256, 0, stream>>>(x, W1l, W1r, xl1h, xr1);

    int nbe = (GE + 255) / 256;
    gl_hist<<<nbe, 256, 0, stream>>>(ei, wpi, cnt, rank);
    gl_scan1<<<(GN + 1023) / 1024, 1024, 0, stream>>>(cnt, rp, bs);
    gl_scan2<<<1, 128, 0, stream>>>(bs, (GN + 1023) / 1024);
    gl_scan3<<<(GN + 255) / 256, 256, 0, stream>>>(rp, bs);
    gl_scatter<<<8192, 256, 0, stream>>>(ei, wpi, eattr, rank, rp, pse);

    gl_L1<<<GN / 4, 256, 0, stream>>>(rp, pse, sea, xl1h, xr1, W1e, att1, b1, esc, lg, h1);
    gl_projB<<<GN / 8, 256, 0, stream>>>(h1, W2l, W2r, xl2h, xr2);
    gl_L2<<<GN / 4, 256, 0, stream>>>(rp, pse, xl2h, xr2, W2e, att2, b2, esc, lg, outf);
    gl_ep<<<(GE2 + 255) / 256, 256, 0, stream>>>(ei, wpi, rank, rp, esc, outf);
}

// Round 22
// 540.537 us; speedup vs baseline: 1.1172x; 1.1172x over previous
//
#include <hip/hip_runtime.h>

#define DEVFN __device__ __forceinline__

constexpr int GN = 100000, GE = 3200000;
constexpr int GE1 = GE + GN;          // 3,300,000
constexpr int GE2 = GE1 + GN;         // 3,400,000
constexpr int GEMB = 128, GHID = 16, GOUT = 32;
constexpr float GNEG = 0.2f;
constexpr float GEA2 = 100000.f / 3300000.f;   // mean(alpha1) = N/E1 exactly

constexpr long long G0 = (long long)GN * GOUT;   //  3,200,000  (out end)
constexpr long long G1 = G0 + 2LL * GE2;         // 10,000,000  (ei2 end; a2 follows)

constexpr unsigned CHUNK = 400000;    // pse slots per XCD-chunk

// ---- ws layout (floats), 56.8 MB ----
constexpr size_t W_ESC  = 0;          // GE2: alpha slots (self at GE+u, GE1+u)
constexpr size_t W_LG   = 3400000;    // GE2: logits (no aliasing in hot loops)
constexpr size_t W_XL1H = 6800000;    // N*HID bf16
constexpr size_t W_XR1  = 7600000;    // N*HID f32
constexpr size_t W_XL2H = 9200000;    // N*OUT bf16
constexpr size_t W_XR2  = 10800000;   // N*OUT f32
constexpr size_t W_RP   = 14000000;   // rowptr N+1 (int)
constexpr size_t W_CNT  = 14100004;   // cnt N (int)
constexpr size_t W_BS   = 14200004;   // scan block sums (256)
constexpr size_t W_SEA  = 14200260;
constexpr size_t W_WPI  = 14200261;
constexpr size_t W_END  = 14200264;

DEVFN int gidx(const int* __restrict__ ei, long long i, int wpi) {
    return ei[(size_t)i * (size_t)wpi];
}
DEVFN unsigned short f2b(float f) {               // f32 -> bf16 RNE
    unsigned u = __float_as_uint(f);
    unsigned r = ((u >> 16) & 1u) + 0x7fffu;
    return (unsigned short)((u + r) >> 16);
}
DEVFN float b2fl(unsigned u) { return __uint_as_float(u << 16); }
DEVFN float b2fh(unsigned u) { return __uint_as_float(u & 0xffff0000u); }

__global__ void gl_sentinel(float* outb) {        // ws too small -> Output 2 ~ 3840
    if (threadIdx.x == 0 && blockIdx.x == 0) outb[G1] = 3840.0f;
}

__global__ void gl_detect(const int* __restrict__ ei, int* flag) {
    int t = threadIdx.x;
    int v = ei[2 * t + 1];
    unsigned long long nz = __ballot(v != 0);
    if (t == 0) *flag = (nz == 0ull) ? 2 : 1;
}

__global__ void gl_sum(const float* __restrict__ p, int n, float* __restrict__ out) {
    float s = 0.f;
    for (int i = blockIdx.x * blockDim.x + threadIdx.x; i < n; i += gridDim.x * blockDim.x)
        s += p[i];
    #pragma unroll
    for (int o = 32; o > 0; o >>= 1) s += __shfl_down(s, o);
    __shared__ float ls[4];
    if ((threadIdx.x & 63) == 0) ls[threadIdx.x >> 6] = s;
    __syncthreads();
    if (threadIdx.x == 0) atomicAdd(out, ls[0] + ls[1] + ls[2] + ls[3]);
}

__global__ __launch_bounds__(256) void gl_projA(const float* __restrict__ x,
        const float* __restrict__ Wl, const float* __restrict__ Wr,
        unsigned short* __restrict__ xlh, float* __restrict__ xr) {
    __shared__ float sWl[GEMB * GHID], sWr[GEMB * GHID], sx[16 * GEMB];
    for (int i = threadIdx.x; i < GEMB * GHID; i += 256) { sWl[i] = Wl[i]; sWr[i] = Wr[i]; }
    int base = blockIdx.x * 16;
    for (int i = threadIdx.x; i < 16 * GEMB; i += 256) sx[i] = x[(size_t)base * GEMB + i];
    __syncthreads();
    int ln = threadIdx.x >> 4, ch = threadIdx.x & 15;
    float al = 0.f, ar = 0.f;
    #pragma unroll 8
    for (int k = 0; k < GEMB; ++k) {
        float xv = sx[ln * GEMB + k];
        al = fmaf(xv, sWl[k * GHID + ch], al);
        ar = fmaf(xv, sWr[k * GHID + ch], ar);
    }
    xlh[(size_t)(base + ln) * GHID + ch] = f2b(al);
    xr[(size_t)(base + ln) * GHID + ch] = ar;
}

__global__ __launch_bounds__(256) void gl_projB(const float* __restrict__ h,
        const float* __restrict__ Wl, const float* __restrict__ Wr,
        unsigned short* __restrict__ xlh, float* __restrict__ xr) {
    __shared__ float sWl[GHID * GOUT], sWr[GHID * GOUT], sx[8 * GHID];
    for (int i = threadIdx.x; i < GHID * GOUT; i += 256) { sWl[i] = Wl[i]; sWr[i] = Wr[i]; }
    int base = blockIdx.x * 8;
    for (int i = threadIdx.x; i < 8 * GHID; i += 256) sx[i] = h[(size_t)base * GHID + i];
    __syncthreads();
    int ln = threadIdx.x >> 5, ch = threadIdx.x & 31;
    float al = 0.f, ar = 0.f;
    #pragma unroll
    for (int k = 0; k < GHID; ++k) {
        float xv = sx[ln * GHID + k];
        al = fmaf(xv, sWl[k * GOUT + ch], al);
        ar = fmaf(xv, sWr[k * GOUT + ch], ar);
    }
    xlh[(size_t)(base + ln) * GOUT + ch] = f2b(al);
    xr[(size_t)(base + ln) * GOUT + ch] = ar;
}

// ---- hist: count per dst, store per-edge local rank ----
__global__ void gl_hist(const int* __restrict__ ei, const int* __restrict__ wpip,
                        int* __restrict__ cnt, int* __restrict__ rank) {
    int e = blockIdx.x * blockDim.x + threadIdx.x;
    if (e >= GE) return;
    int wpi = *wpip;
    int dst = gidx(ei, (long long)GE + e, wpi);
    rank[e] = atomicAdd(&cnt[dst], 1);
}

__global__ __launch_bounds__(1024) void gl_scan1(const int* __restrict__ cnt,
                                                 int* __restrict__ rp, int* __restrict__ bs) {
    __shared__ int s[1024];
    int t = threadIdx.x, u = blockIdx.x * 1024 + t;
    s[t] = (u < GN) ? cnt[u] : 0;
    __syncthreads();
    for (int off = 1; off < 1024; off <<= 1) {
        int a = (t >= off) ? s[t - off] : 0;
        __syncthreads();
        s[t] += a;
        __syncthreads();
    }
    if (u < GN) rp[u + 1] = s[t];
    if (t == 1023) bs[blockIdx.x] = s[1023];
}
__global__ void gl_scan2(int* __restrict__ bs, int nb) {
    __shared__ int s[128];
    int t = threadIdx.x;
    s[t] = (t < nb) ? bs[t] : 0;
    __syncthreads();
    for (int off = 1; off < 128; off <<= 1) {
        int a = (t >= off) ? s[t - off] : 0;
        __syncthreads();
        s[t] += a;
        __syncthreads();
    }
    if (t < nb) bs[t] = (t == 0) ? 0 : s[t - 1];
}
__global__ void gl_scan3(int* __restrict__ rp, const int* __restrict__ bs) {
    int u = blockIdx.x * blockDim.x + threadIdx.x;
    if (u < GN) rp[u + 1] += bs[u >> 10];
    if (u == 0) rp[0] = 0;
}

// ---- slots: inv[e] = rp[dst] + rank[e] ----
__global__ void gl_slots(const int* __restrict__ ei, const int* __restrict__ wpip,
                         const int* __restrict__ rank, const int* __restrict__ rp,
                         int* __restrict__ inv) {
    int e = blockIdx.x * blockDim.x + threadIdx.x;
    if (e >= GE) return;
    int wpi = *wpip;
    int dst = gidx(ei, (long long)GE + e, wpi);
    inv[e] = rp[dst] + rank[e];
}

// ---- scatter: chunk-per-XCD (full-line writeback), inv-driven ----
__global__ __launch_bounds__(256) void gl_scatter(const int* __restrict__ ei,
        const int* __restrict__ wpip, const float* __restrict__ eattr,
        const int* __restrict__ inv, int2* __restrict__ pse) {
    int wpi = *wpip;
    unsigned ck = blockIdx.x & 7;
    int stride = (gridDim.x >> 3) * 256;
    for (int e = (blockIdx.x >> 3) * 256 + threadIdx.x; e < GE; e += stride) {
        int slot = inv[e];
        if ((unsigned)slot / CHUNK == ck) {
            int src = gidx(ei, e, wpi);
            pse[slot] = make_int2(src, __float_as_int(eattr[e]));
        }
    }
}

// ------- fused layer 1: 4 lanes/edge, depth-2 gather pipeline (HID=16) -------
__global__ __launch_bounds__(256) void gl_L1(const int* __restrict__ rp,
        const int2* __restrict__ pse, const float* __restrict__ sea,
        const unsigned short* __restrict__ xlh, const float* __restrict__ xr,
        const float* __restrict__ We, const float* __restrict__ att,
        const float* __restrict__ b1, float* __restrict__ esc,
        float* __restrict__ lg, float* __restrict__ h1) {
    int u = blockIdx.x * 4 + (threadIdx.x >> 6);
    int lane = threadIdx.x & 63, sg = lane >> 2, ln4 = lane & 3;
    int beg = rp[u], end = rp[u + 1];
    float4 we = *(const float4*)(We + ln4 * 4);
    float4 at = *(const float4*)(att + ln4 * 4);
    float4 xru = *(const float4*)(xr + (size_t)u * GHID + ln4 * 4);
    float mx = -3.0e38f, pd = 0.f;
    float4 acc = make_float4(0.f, 0.f, 0.f, 0.f);
    int i = beg + sg;
    int2 p = (i < end) ? pse[i] : make_int2(0, 0);
    uint2 h = (i < end) ? *(const uint2*)(xlh + (size_t)p.x * GHID + ln4 * 4)
                        : make_uint2(0, 0);
    for (; i < end; i += 16) {
        int inx = i + 16;
        int2 pn = (inx < end) ? pse[inx] : make_int2(0, 0);
        uint2 hn = (inx < end) ? *(const uint2*)(xlh + (size_t)pn.x * GHID + ln4 * 4)
                               : make_uint2(0, 0);
        float ea = __int_as_float(p.y);
        float x0 = b2fl(h.x), x1 = b2fh(h.x), x2 = b2fl(h.y), x3 = b2fh(h.y);
        float v, s = 0.f;
        v = x0 + xru.x + ea * we.x; v = v > 0.f ? v : GNEG * v; s = fmaf(v, at.x, s);
        v = x1 + xru.y + ea * we.y; v = v > 0.f ? v : GNEG * v; s = fmaf(v, at.y, s);
        v = x2 + xru.z + ea * we.z; v = v > 0.f ? v : GNEG * v; s = fmaf(v, at.z, s);
        v = x3 + xru.w + ea * we.w; v = v > 0.f ? v : GNEG * v; s = fmaf(v, at.w, s);
        s += __shfl_xor(s, 1); s += __shfl_xor(s, 2);
        if (ln4 == 0) lg[i] = s;
        float nm = fmaxf(mx, s);
        float sc = __expf(mx - nm), pp = __expf(s - nm);
        pd = pd * sc + pp;
        acc.x = acc.x * sc + pp * x0; acc.y = acc.y * sc + pp * x1;
        acc.z = acc.z * sc + pp * x2; acc.w = acc.w * sc + pp * x3;
        mx = nm;
        p = pn; h = hn;
    }
    float lgself = 0.f;
    if (sg == 0) {                                  // self-loop (ea = mean(edge_attr))
        uint2 hs = *(const uint2*)(xlh + (size_t)u * GHID + ln4 * 4);
        float ea = sea[0] * (1.f / (float)GE);
        float x0 = b2fl(hs.x), x1 = b2fh(hs.x), x2 = b2fl(hs.y), x3 = b2fh(hs.y);
        float v, s = 0.f;
        v = x0 + xru.x + ea * we.x; v = v > 0.f ? v : GNEG * v; s = fmaf(v, at.x, s);
        v = x1 + xru.y + ea * we.y; v = v > 0.f ? v : GNEG * v; s = fmaf(v, at.y, s);
        v = x2 + xru.z + ea * we.z; v = v > 0.f ? v : GNEG * v; s = fmaf(v, at.z, s);
        v = x3 + xru.w + ea * we.w; v = v > 0.f ? v : GNEG * v; s = fmaf(v, at.w, s);
        s += __shfl_xor(s, 1); s += __shfl_xor(s, 2);
        lgself = s;
        float nm = fmaxf(mx, s);
        float sc = __expf(mx - nm), pp = __expf(s - nm);
        pd = pd * sc + pp;
        acc.x = acc.x * sc + pp * x0; acc.y = acc.y * sc + pp * x1;
        acc.z = acc.z * sc + pp * x2; acc.w = acc.w * sc + pp * x3;
        mx = nm;
    }
    #pragma unroll
    for (int o = 4; o <= 32; o <<= 1) {             // merge 16 subgroups
        float mo = __shfl_xor(mx, o), po = __shfl_xor(pd, o);
        float a0 = __shfl_xor(acc.x, o), a1 = __shfl_xor(acc.y, o);
        float a2 = __shfl_xor(acc.z, o), a3 = __shfl_xor(acc.w, o);
        float nm = fmaxf(mx, mo);
        float sa = __expf(mx - nm), sb = __expf(mo - nm);
        pd = pd * sa + po * sb;
        acc.x = acc.x * sa + a0 * sb; acc.y = acc.y * sa + a1 * sb;
        acc.z = acc.z * sa + a2 * sb; acc.w = acc.w * sa + a3 * sb;
        mx = nm;
    }
    float dinv = 1.f / pd;
    __threadfence_block();
    for (int j = beg + lane; j < end; j += 64)      // alpha pass (coalesced)
        esc[j] = __expf(lg[j] - mx) * dinv;
    if (lane == 0) esc[GE + u] = __expf(lgself - mx) * dinv;
    if (lane < 4) {
        float4 b = *(const float4*)(b1 + lane * 4);
        float4 o;
        o.x = acc.x * dinv + b.x; o.y = acc.y * dinv + b.y;
        o.z = acc.z * dinv + b.z; o.w = acc.w * dinv + b.w;
        o.x = o.x > 0.f ? o.x : 0.f; o.y = o.y > 0.f ? o.y : 0.f;
        o.z = o.z > 0.f ? o.z : 0.f; o.w = o.w > 0.f ? o.w : 0.f;
        *(float4*)(h1 + (size_t)u * GHID + lane * 4) = o;   // fused bias+relu
    }
}

// ------- fused layer 2: 8 lanes/edge, depth-2 gather pipeline (OUT=32) -------
__global__ __launch_bounds__(256) void gl_L2(const int* __restrict__ rp,
        const int2* __restrict__ pse,
        const unsigned short* __restrict__ xlh, const float* __restrict__ xr,
        const float* __restrict__ We, const float* __restrict__ att,
        const float* __restrict__ b2, float* __restrict__ esc,
        float* __restrict__ lg, float* __restrict__ out0) {
    int u = blockIdx.x * 4 + (threadIdx.x >> 6);
    int lane = threadIdx.x & 63, sg = lane >> 3, ln8 = lane & 7;
    int beg = rp[u], end = rp[u + 1];
    float4 we = *(const float4*)(We + ln8 * 4);
    float4 at = *(const float4*)(att + ln8 * 4);
    float4 xru = *(const float4*)(xr + (size_t)u * GOUT + ln8 * 4);
    float mx = -3.0e38f, pd = 0.f;
    float4 acc = make_float4(0.f, 0.f, 0.f, 0.f);
    int i = beg + sg;
    int2 p = (i < end) ? pse[i] : make_int2(0, 0);
    float ea = (i < end) ? esc[i] : 0.f;
    uint2 h = (i < end) ? *(const uint2*)(xlh + (size_t)p.x * GOUT + ln8 * 4)
                        : make_uint2(0, 0);
    for (; i < end; i += 8) {
        int inx = i + 8;
        int2 pn = (inx < end) ? pse[inx] : make_int2(0, 0);
        float ean = (inx < end) ? esc[inx] : 0.f;
        uint2 hn = (inx < end) ? *(const uint2*)(xlh + (size_t)pn.x * GOUT + ln8 * 4)
                               : make_uint2(0, 0);
        float x0 = b2fl(h.x), x1 = b2fh(h.x), x2 = b2fl(h.y), x3 = b2fh(h.y);
        float v, s = 0.f;
        v = x0 + xru.x + ea * we.x; v = v > 0.f ? v : GNEG * v; s = fmaf(v, at.x, s);
        v = x1 + xru.y + ea * we.y; v = v > 0.f ? v : GNEG * v; s = fmaf(v, at.y, s);
        v = x2 + xru.z + ea * we.z; v = v > 0.f ? v : GNEG * v; s = fmaf(v, at.z, s);
        v = x3 + xru.w + ea * we.w; v = v > 0.f ? v : GNEG * v; s = fmaf(v, at.w, s);
        s += __shfl_xor(s, 1); s += __shfl_xor(s, 2); s += __shfl_xor(s, 4);
        if (ln8 == 0) lg[i] = s;
        float nm = fmaxf(mx, s);
        float sc = __expf(mx - nm), pp = __expf(s - nm);
        pd = pd * sc + pp;
        acc.x = acc.x * sc + pp * x0; acc.y = acc.y * sc + pp * x1;
        acc.z = acc.z * sc + pp * x2; acc.w = acc.w * sc + pp * x3;
        mx = nm;
        p = pn; ea = ean; h = hn;
    }
    float lgs = 0.f;
    if (sg < 2) {   // two self-loops: sg0 -> ea=alpha1_self, sg1 -> ea=N/E1
        float eas = (sg == 0) ? esc[GE + u] : GEA2;
        uint2 hs = *(const uint2*)(xlh + (size_t)u * GOUT + ln8 * 4);
        float x0 = b2fl(hs.x), x1 = b2fh(hs.x), x2 = b2fl(hs.y), x3 = b2fh(hs.y);
        float v, s = 0.f;
        v = x0 + xru.x + eas * we.x; v = v > 0.f ? v : GNEG * v; s = fmaf(v, at.x, s);
        v = x1 + xru.y + eas * we.y; v = v > 0.f ? v : GNEG * v; s = fmaf(v, at.y, s);
        v = x2 + xru.z + eas * we.z; v = v > 0.f ? v : GNEG * v; s = fmaf(v, at.z, s);
        v = x3 + xru.w + eas * we.w; v = v > 0.f ? v : GNEG * v; s = fmaf(v, at.w, s);
        s += __shfl_xor(s, 1); s += __shfl_xor(s, 2); s += __shfl_xor(s, 4);
        lgs = s;
        float nm = fmaxf(mx, s);
        float sc = __expf(mx - nm), pp = __expf(s - nm);
        pd = pd * sc + pp;
        acc.x = acc.x * sc + pp * x0; acc.y = acc.y * sc + pp * x1;
        acc.z = acc.z * sc + pp * x2; acc.w = acc.w * sc + pp * x3;
        mx = nm;
    }
    #pragma unroll
    for (int o = 8; o <= 32; o <<= 1) {             // merge 8 subgroups
        float mo = __shfl_xor(mx, o), po = __shfl_xor(pd, o);
        float a0 = __shfl_xor(acc.x, o), a1 = __shfl_xor(acc.y, o);
        float a2 = __shfl_xor(acc.z, o), a3 = __shfl_xor(acc.w, o);
        float nm = fmaxf(mx, mo);
        float sa = __expf(mx - nm), sb = __expf(mo - nm);
        pd = pd * sa + po * sb;
        acc.x = acc.x * sa + a0 * sb; acc.y = acc.y * sa + a1 * sb;
        acc.z = acc.z * sa + a2 * sb; acc.w = acc.w * sa + a3 * sb;
        mx = nm;
    }
    float dinv = 1.f / pd;
    __threadfence_block();
    for (int j = beg + lane; j < end; j += 64)      // alpha2 pass (coalesced)
        esc[j] = __expf(lg[j] - mx) * dinv;
    if (lane == 0) esc[GE + u]  = __expf(lgs - mx) * dinv;
    if (lane == 8) esc[GE1 + u] = __expf(lgs - mx) * dinv;
    if (lane < 8) {
        float4 b = *(const float4*)(b2 + lane * 4);
        float4 o;
        o.x = acc.x * dinv + b.x; o.y = acc.y * dinv + b.y;
        o.z = acc.z * dinv + b.z; o.w = acc.w * dinv + b.w;
        *(float4*)(out0 + (size_t)u * GOUT + lane * 4) = o;
    }
}

// fused epilogue: ei2 (2 floats) + a2 (1 float) per index, one pass.
// inv[c] (at outb[G1+c]) is read before this thread overwrites it with a2[c].
__global__ void gl_ep(const int* __restrict__ ei, const int* __restrict__ wpip,
                      const int* __restrict__ inv, const float* __restrict__ esc,
                      float* __restrict__ outb) {
    int c = blockIdx.x * blockDim.x + threadIdx.x;
    if (c >= GE2) return;
    int wpi = *wpip;
    int s, dd;
    float av;
    if (c < GE) {
        s = gidx(ei, c, wpi);
        dd = gidx(ei, (long long)GE + c, wpi);
        av = esc[inv[c]];
    } else if (c < GE1) {
        s = dd = c - GE;
        av = esc[c];
    } else {
        s = dd = c - GE1;
        av = esc[c];
    }
    outb[G0 + c]       = (float)s;
    outb[G0 + GE2 + c] = (float)dd;
    outb[G1 + c]       = av;
}

extern "C" void kernel_launch(void* const* d_in, const int* in_sizes, int n_in,
                              void* d_out, int out_size, void* d_ws, size_t ws_size,
                              hipStream_t stream) {
    const float* x     = (const float*)d_in[0];
    const int*   ei    = (const int*)d_in[1];
    const float* eattr = (const float*)d_in[2];
    const float* W1l   = (const float*)d_in[3];
    const float* W1r   = (const float*)d_in[4];
    const float* W1e   = (const float*)d_in[5];
    const float* att1  = (const float*)d_in[6];
    const float* b1    = (const float*)d_in[7];
    const float* W2l   = (const float*)d_in[8];
    const float* W2r   = (const float*)d_in[9];
    const float* W2e   = (const float*)d_in[10];
    const float* att2  = (const float*)d_in[11];
    const float* b2    = (const float*)d_in[12];
    float* outf = (float*)d_out;

    float* ws = (float*)d_ws;
    if (W_END * sizeof(float) > ws_size) {          // 56.8 MB needed
        gl_sentinel<<<1, 64, 0, stream>>>(outf);
        return;
    }

    float*          esc  = ws + W_ESC;
    float*          lg   = ws + W_LG;
    unsigned short* xl1h = (unsigned short*)(ws + W_XL1H);
    float*          xr1  = ws + W_XR1;
    unsigned short* xl2h = (unsigned short*)(ws + W_XL2H);
    float*          xr2  = ws + W_XR2;
    int*            rp   = (int*)(ws + W_RP);
    int*            cnt  = (int*)(ws + W_CNT);
    int*            bs   = (int*)(ws + W_BS);
    float*          sea  = ws + W_SEA;
    int*            wpi  = (int*)(ws + W_WPI);

    // d_out scratch (strictly sequential reuse):
    //   rank: [G0, G0+GE) — consumed by gl_slots, THEN pse overwrites.
    //   pse : [G0, G0+6.4M) = ei2 region — killed by gl_ep.
    //   inv : [G1, G1+GE)   = a2 region  — read-then-overwritten by gl_ep.
    int*   rank = (int*)(outf + G0);
    int2*  pse  = (int2*)(outf + G0);
    int*   inv  = (int*)(outf + G1);
    float* h1   = outf;                             // chunk0, killed by L2's out0

    hipMemsetAsync(cnt, 0, GN * sizeof(int), stream);
    hipMemsetAsync(sea, 0, 2 * sizeof(float), stream);

    gl_detect<<<1, 64, 0, stream>>>(ei, wpi);
    gl_sum<<<1024, 256, 0, stream>>>(eattr, GE, sea);
    gl_projA<<<GN / 16, 256, 0, stream>>>(x, W1l, W1r, xl1h, xr1);

    int nbe = (GE + 255) / 256;
    gl_hist<<<nbe, 256, 0, stream>>>(ei, wpi, cnt, rank);
    gl_scan1<<<(GN + 1023) / 1024, 1024, 0, stream>>>(cnt, rp, bs);
    gl_scan2<<<1, 128, 0, stream>>>(bs, (GN + 1023) / 1024);
    gl_scan3<<<(GN + 255) / 256, 256, 0, stream>>>(rp, bs);
    gl_slots<<<nbe, 256, 0, stream>>>(ei, wpi, rank, rp, inv);
    gl_scatter<<<8192, 256, 0, stream>>>(ei, wpi, eattr, inv, pse);

    gl_L1<<<GN / 4, 256, 0, stream>>>(rp, pse, sea, xl1h, xr1, W1e, att1, b1, esc, lg, h1);
    gl_projB<<<GN / 8, 256, 0, stream>>>(h1, W2l, W2r, xl2h, xr2);
    gl_L2<<<GN / 4, 256, 0, stream>>>(rp, pse, xl2h, xr2, W2e, att2, b2, esc, lg, outf);
    gl_ep<<<(GE2 + 255) / 256, 256, 0, stream>>>(ei, wpi, inv, esc, outf);
}

// Round 23
// 535.422 us; speedup vs baseline: 1.1279x; 1.0096x over previous
//
#include <hip/hip_runtime.h>

#define DEVFN __device__ __forceinline__

constexpr int GN = 100000, GE = 3200000;
constexpr int GE1 = GE + GN;          // 3,300,000
constexpr int GE2 = GE1 + GN;         // 3,400,000
constexpr int GEMB = 128, GHID = 16, GOUT = 32;
constexpr float GNEG = 0.2f;
constexpr float GEA2 = 100000.f / 3300000.f;   // mean(alpha1) = N/E1 exactly

constexpr long long G0 = (long long)GN * GOUT;   //  3,200,000  (out end)
constexpr long long G1 = G0 + 2LL * GE2;         // 10,000,000  (ei2 end; a2 follows)

constexpr unsigned CHUNK = 400000;    // pse slots per XCD-chunk

// ---- ws layout (floats), 56.8 MB ----
constexpr size_t W_ESC  = 0;          // GE2: alpha slots (self at GE+u, GE1+u)
constexpr size_t W_LG   = 3400000;    // GE2: logits
constexpr size_t W_XL1H = 6800000;    // N*HID bf16
constexpr size_t W_XR1  = 7600000;    // N*HID f32
constexpr size_t W_XL2H = 9200000;    // N*OUT bf16
constexpr size_t W_XR2  = 10800000;   // N*OUT f32
constexpr size_t W_RP   = 14000000;   // rowptr N+1 (int)
constexpr size_t W_CNT  = 14100004;   // cnt N (int)
constexpr size_t W_BS   = 14200004;   // scan block sums (256)
constexpr size_t W_SEA  = 14200260;
constexpr size_t W_WPI  = 14200261;
constexpr size_t W_END  = 14200264;

DEVFN int gidx(const int* __restrict__ ei, long long i, int wpi) {
    return ei[(size_t)i * (size_t)wpi];
}
DEVFN unsigned short f2b(float f) {               // f32 -> bf16 RNE
    unsigned u = __float_as_uint(f);
    unsigned r = ((u >> 16) & 1u) + 0x7fffu;
    return (unsigned short)((u + r) >> 16);
}
DEVFN float b2fl(unsigned u) { return __uint_as_float(u << 16); }
DEVFN float b2fh(unsigned u) { return __uint_as_float(u & 0xffff0000u); }

// 8-wide leaky-relu dot for one edge-chunk of 8 channels
DEVFN float dot8(uint4 h, const float* xru, const float* we, const float* at,
                 float ea, float* xs) {
    float s = 0.f;
    unsigned w[4] = {h.x, h.y, h.z, h.w};
    #pragma unroll
    for (int q = 0; q < 4; ++q) {
        float xa = b2fl(w[q]), xb = b2fh(w[q]);
        float v;
        v = xa + xru[2 * q]     + ea * we[2 * q];     v = v > 0.f ? v : GNEG * v;
        s = fmaf(v, at[2 * q], s);
        v = xb + xru[2 * q + 1] + ea * we[2 * q + 1]; v = v > 0.f ? v : GNEG * v;
        s = fmaf(v, at[2 * q + 1], s);
        xs[2 * q] = xa; xs[2 * q + 1] = xb;
    }
    return s;
}

__global__ void gl_sentinel(float* outb) {        // ws too small -> Output 2 ~ 3840
    if (threadIdx.x == 0 && blockIdx.x == 0) outb[G1] = 3840.0f;
}

__global__ void gl_detect(const int* __restrict__ ei, int* flag) {
    int t = threadIdx.x;
    int v = ei[2 * t + 1];
    unsigned long long nz = __ballot(v != 0);
    if (t == 0) *flag = (nz == 0ull) ? 2 : 1;
}

__global__ void gl_sum(const float* __restrict__ p, int n, float* __restrict__ out) {
    float s = 0.f;
    for (int i = blockIdx.x * blockDim.x + threadIdx.x; i < n; i += gridDim.x * blockDim.x)
        s += p[i];
    #pragma unroll
    for (int o = 32; o > 0; o >>= 1) s += __shfl_down(s, o);
    __shared__ float ls[4];
    if ((threadIdx.x & 63) == 0) ls[threadIdx.x >> 6] = s;
    __syncthreads();
    if (threadIdx.x == 0) atomicAdd(out, ls[0] + ls[1] + ls[2] + ls[3]);
}

__global__ __launch_bounds__(256) void gl_projA(const float* __restrict__ x,
        const float* __restrict__ Wl, const float* __restrict__ Wr,
        unsigned short* __restrict__ xlh, float* __restrict__ xr) {
    __shared__ float sWl[GEMB * GHID], sWr[GEMB * GHID], sx[16 * GEMB];
    for (int i = threadIdx.x; i < GEMB * GHID; i += 256) { sWl[i] = Wl[i]; sWr[i] = Wr[i]; }
    int base = blockIdx.x * 16;
    for (int i = threadIdx.x; i < 16 * GEMB; i += 256) sx[i] = x[(size_t)base * GEMB + i];
    __syncthreads();
    int ln = threadIdx.x >> 4, ch = threadIdx.x & 15;
    float al = 0.f, ar = 0.f;
    #pragma unroll 8
    for (int k = 0; k < GEMB; ++k) {
        float xv = sx[ln * GEMB + k];
        al = fmaf(xv, sWl[k * GHID + ch], al);
        ar = fmaf(xv, sWr[k * GHID + ch], ar);
    }
    xlh[(size_t)(base + ln) * GHID + ch] = f2b(al);
    xr[(size_t)(base + ln) * GHID + ch] = ar;
}

__global__ __launch_bounds__(256) void gl_projB(const float* __restrict__ h,
        const float* __restrict__ Wl, const float* __restrict__ Wr,
        unsigned short* __restrict__ xlh, float* __restrict__ xr) {
    __shared__ float sWl[GHID * GOUT], sWr[GHID * GOUT], sx[8 * GHID];
    for (int i = threadIdx.x; i < GHID * GOUT; i += 256) { sWl[i] = Wl[i]; sWr[i] = Wr[i]; }
    int base = blockIdx.x * 8;
    for (int i = threadIdx.x; i < 8 * GHID; i += 256) sx[i] = h[(size_t)base * GHID + i];
    __syncthreads();
    int ln = threadIdx.x >> 5, ch = threadIdx.x & 31;
    float al = 0.f, ar = 0.f;
    #pragma unroll
    for (int k = 0; k < GHID; ++k) {
        float xv = sx[ln * GHID + k];
        al = fmaf(xv, sWl[k * GOUT + ch], al);
        ar = fmaf(xv, sWr[k * GOUT + ch], ar);
    }
    xlh[(size_t)(base + ln) * GOUT + ch] = f2b(al);
    xr[(size_t)(base + ln) * GOUT + ch] = ar;
}

// ---- hist ----
__global__ void gl_hist(const int* __restrict__ ei, const int* __restrict__ wpip,
                        int* __restrict__ cnt, int* __restrict__ rank) {
    int e = blockIdx.x * blockDim.x + threadIdx.x;
    if (e >= GE) return;
    int wpi = *wpip;
    int dst = gidx(ei, (long long)GE + e, wpi);
    rank[e] = atomicAdd(&cnt[dst], 1);
}

__global__ __launch_bounds__(1024) void gl_scan1(const int* __restrict__ cnt,
                                                 int* __restrict__ rp, int* __restrict__ bs) {
    __shared__ int s[1024];
    int t = threadIdx.x, u = blockIdx.x * 1024 + t;
    s[t] = (u < GN) ? cnt[u] : 0;
    __syncthreads();
    for (int off = 1; off < 1024; off <<= 1) {
        int a = (t >= off) ? s[t - off] : 0;
        __syncthreads();
        s[t] += a;
        __syncthreads();
    }
    if (u < GN) rp[u + 1] = s[t];
    if (t == 1023) bs[blockIdx.x] = s[1023];
}
__global__ void gl_scan2(int* __restrict__ bs, int nb) {
    __shared__ int s[128];
    int t = threadIdx.x;
    s[t] = (t < nb) ? bs[t] : 0;
    __syncthreads();
    for (int off = 1; off < 128; off <<= 1) {
        int a = (t >= off) ? s[t - off] : 0;
        __syncthreads();
        s[t] += a;
        __syncthreads();
    }
    if (t < nb) bs[t] = (t == 0) ? 0 : s[t - 1];
}
__global__ void gl_scan3(int* __restrict__ rp, const int* __restrict__ bs) {
    int u = blockIdx.x * blockDim.x + threadIdx.x;
    if (u < GN) rp[u + 1] += bs[u >> 10];
    if (u == 0) rp[0] = 0;
}

// ---- slots ----
__global__ void gl_slots(const int* __restrict__ ei, const int* __restrict__ wpip,
                         const int* __restrict__ rank, const int* __restrict__ rp,
                         int* __restrict__ inv) {
    int e = blockIdx.x * blockDim.x + threadIdx.x;
    if (e >= GE) return;
    int wpi = *wpip;
    int dst = gidx(ei, (long long)GE + e, wpi);
    inv[e] = rp[dst] + rank[e];
}

// ---- scatter: chunk-per-XCD, inv-driven ----
__global__ __launch_bounds__(256) void gl_scatter(const int* __restrict__ ei,
        const int* __restrict__ wpip, const float* __restrict__ eattr,
        const int* __restrict__ inv, int2* __restrict__ pse) {
    int wpi = *wpip;
    unsigned ck = blockIdx.x & 7;
    int stride = (gridDim.x >> 3) * 256;
    for (int e = (blockIdx.x >> 3) * 256 + threadIdx.x; e < GE; e += stride) {
        int slot = inv[e];
        if ((unsigned)slot / CHUNK == ck) {
            int src = gidx(ei, e, wpi);
            pse[slot] = make_int2(src, __float_as_int(eattr[e]));
        }
    }
}

// ------- layer 1: 2 lanes/edge (8ch, uint4), 32 edges in flight (HID=16) -------
__global__ __launch_bounds__(256) void gl_L1(const int* __restrict__ rp,
        const int2* __restrict__ pse, const float* __restrict__ sea,
        const unsigned short* __restrict__ xlh, const float* __restrict__ xr,
        const float* __restrict__ We, const float* __restrict__ att,
        const float* __restrict__ b1, float* __restrict__ esc,
        float* __restrict__ lg, float* __restrict__ h1) {
    int u = blockIdx.x * 4 + (threadIdx.x >> 6);
    int lane = threadIdx.x & 63, sg = lane >> 1, ln2 = lane & 1;
    int beg = rp[u], end = rp[u + 1];
    float we[8], at[8], xru[8];
    #pragma unroll
    for (int q = 0; q < 8; ++q) {
        we[q] = We[ln2 * 8 + q];
        at[q] = att[ln2 * 8 + q];
        xru[q] = xr[(size_t)u * GHID + ln2 * 8 + q];
    }
    float mx = -3.0e38f, pd = 0.f;
    float acc[8] = {0, 0, 0, 0, 0, 0, 0, 0};
    int i = beg + sg;
    int2 p = (i < end) ? pse[i] : make_int2(0, 0);
    uint4 h = (i < end) ? *(const uint4*)(xlh + (size_t)p.x * GHID + ln2 * 8)
                        : make_uint4(0, 0, 0, 0);
    for (; i < end; i += 32) {
        int inx = i + 32;
        int2 pn = (inx < end) ? pse[inx] : make_int2(0, 0);
        uint4 hn = (inx < end) ? *(const uint4*)(xlh + (size_t)pn.x * GHID + ln2 * 8)
                               : make_uint4(0, 0, 0, 0);
        float xs[8];
        float s = dot8(h, xru, we, at, __int_as_float(p.y), xs);
        s += __shfl_xor(s, 1);
        if (ln2 == 0) lg[i] = s;
        float nm = fmaxf(mx, s);
        float sc = __expf(mx - nm), pp = __expf(s - nm);
        pd = pd * sc + pp;
        #pragma unroll
        for (int q = 0; q < 8; ++q) acc[q] = acc[q] * sc + pp * xs[q];
        mx = nm;
        p = pn; h = hn;
    }
    float lgself = 0.f;
    if (sg == 0) {                                  // self-loop (ea = mean(edge_attr))
        uint4 hs = *(const uint4*)(xlh + (size_t)u * GHID + ln2 * 8);
        float xs[8];
        float s = dot8(hs, xru, we, at, sea[0] * (1.f / (float)GE), xs);
        s += __shfl_xor(s, 1);
        lgself = s;
        float nm = fmaxf(mx, s);
        float sc = __expf(mx - nm), pp = __expf(s - nm);
        pd = pd * sc + pp;
        #pragma unroll
        for (int q = 0; q < 8; ++q) acc[q] = acc[q] * sc + pp * xs[q];
        mx = nm;
    }
    #pragma unroll
    for (int o = 2; o <= 32; o <<= 1) {             // merge 32 subgroups
        float mo = __shfl_xor(mx, o), po = __shfl_xor(pd, o);
        float ao[8];
        #pragma unroll
        for (int q = 0; q < 8; ++q) ao[q] = __shfl_xor(acc[q], o);
        float nm = fmaxf(mx, mo);
        float sa = __expf(mx - nm), sb = __expf(mo - nm);
        pd = pd * sa + po * sb;
        #pragma unroll
        for (int q = 0; q < 8; ++q) acc[q] = acc[q] * sa + ao[q] * sb;
        mx = nm;
    }
    float dinv = 1.f / pd;
    __threadfence_block();
    for (int j = beg + lane; j < end; j += 64)      // alpha pass (coalesced)
        esc[j] = __expf(lg[j] - mx) * dinv;
    if (lane == 0) esc[GE + u] = __expf(lgself - mx) * dinv;
    if (lane < 2) {
        float o[8];
        #pragma unroll
        for (int q = 0; q < 8; ++q) {
            o[q] = acc[q] * dinv + b1[lane * 8 + q];
            o[q] = o[q] > 0.f ? o[q] : 0.f;         // fused bias+relu
        }
        *(float4*)(h1 + (size_t)u * GHID + lane * 8)     = make_float4(o[0], o[1], o[2], o[3]);
        *(float4*)(h1 + (size_t)u * GHID + lane * 8 + 4) = make_float4(o[4], o[5], o[6], o[7]);
    }
}

// ------- layer 2: 4 lanes/edge (8ch, uint4), 16 edges in flight (OUT=32) -------
__global__ __launch_bounds__(256) void gl_L2(const int* __restrict__ rp,
        const int2* __restrict__ pse,
        const unsigned short* __restrict__ xlh, const float* __restrict__ xr,
        const float* __restrict__ We, const float* __restrict__ att,
        const float* __restrict__ b2, float* __restrict__ esc,
        float* __restrict__ lg, float* __restrict__ out0) {
    int u = blockIdx.x * 4 + (threadIdx.x >> 6);
    int lane = threadIdx.x & 63, sg = lane >> 2, ln4 = lane & 3;
    int beg = rp[u], end = rp[u + 1];
    float we[8], at[8], xru[8];
    #pragma unroll
    for (int q = 0; q < 8; ++q) {
        we[q] = We[ln4 * 8 + q];
        at[q] = att[ln4 * 8 + q];
        xru[q] = xr[(size_t)u * GOUT + ln4 * 8 + q];
    }
    float mx = -3.0e38f, pd = 0.f;
    float acc[8] = {0, 0, 0, 0, 0, 0, 0, 0};
    int i = beg + sg;
    int2 p = (i < end) ? pse[i] : make_int2(0, 0);
    float ea = (i < end) ? esc[i] : 0.f;
    uint4 h = (i < end) ? *(const uint4*)(xlh + (size_t)p.x * GOUT + ln4 * 8)
                        : make_uint4(0, 0, 0, 0);
    for (; i < end; i += 16) {
        int inx = i + 16;
        int2 pn = (inx < end) ? pse[inx] : make_int2(0, 0);
        float ean = (inx < end) ? esc[inx] : 0.f;
        uint4 hn = (inx < end) ? *(const uint4*)(xlh + (size_t)pn.x * GOUT + ln4 * 8)
                               : make_uint4(0, 0, 0, 0);
        float xs[8];
        float s = dot8(h, xru, we, at, ea, xs);
        s += __shfl_xor(s, 1); s += __shfl_xor(s, 2);
        if (ln4 == 0) lg[i] = s;
        float nm = fmaxf(mx, s);
        float sc = __expf(mx - nm), pp = __expf(s - nm);
        pd = pd * sc + pp;
        #pragma unroll
        for (int q = 0; q < 8; ++q) acc[q] = acc[q] * sc + pp * xs[q];
        mx = nm;
        p = pn; ea = ean; h = hn;
    }
    float lgs = 0.f;
    if (sg < 2) {   // two self-loops: sg0 -> ea=alpha1_self, sg1 -> ea=N/E1
        float eas = (sg == 0) ? esc[GE + u] : GEA2;
        uint4 hs = *(const uint4*)(xlh + (size_t)u * GOUT + ln4 * 8);
        float xs[8];
        float s = dot8(hs, xru, we, at, eas, xs);
        s += __shfl_xor(s, 1); s += __shfl_xor(s, 2);
        lgs = s;
        float nm = fmaxf(mx, s);
        float sc = __expf(mx - nm), pp = __expf(s - nm);
        pd = pd * sc + pp;
        #pragma unroll
        for (int q = 0; q < 8; ++q) acc[q] = acc[q] * sc + pp * xs[q];
        mx = nm;
    }
    #pragma unroll
    for (int o = 4; o <= 32; o <<= 1) {             // merge 16 subgroups
        float mo = __shfl_xor(mx, o), po = __shfl_xor(pd, o);
        float ao[8];
        #pragma unroll
        for (int q = 0; q < 8; ++q) ao[q] = __shfl_xor(acc[q], o);
        float nm = fmaxf(mx, mo);
        float sa = __expf(mx - nm), sb = __expf(mo - nm);
        pd = pd * sa + po * sb;
        #pragma unroll
        for (int q = 0; q < 8; ++q) acc[q] = acc[q] * sa + ao[q] * sb;
        mx = nm;
    }
    float dinv = 1.f / pd;
    __threadfence_block();
    for (int j = beg + lane; j < end; j += 64)      // alpha2 pass (coalesced)
        esc[j] = __expf(lg[j] - mx) * dinv;
    if (lane == 0) esc[GE + u]  = __expf(lgs - mx) * dinv;
    if (lane == 4) esc[GE1 + u] = __expf(lgs - mx) * dinv;
    if (lane < 4) {
        float o[8];
        #pragma unroll
        for (int q = 0; q < 8; ++q) o[q] = acc[q] * dinv + b2[lane * 8 + q];
        *(float4*)(out0 + (size_t)u * GOUT + lane * 8)     = make_float4(o[0], o[1], o[2], o[3]);
        *(float4*)(out0 + (size_t)u * GOUT + lane * 8 + 4) = make_float4(o[4], o[5], o[6], o[7]);
    }
}

// fused epilogue
__global__ void gl_ep(const int* __restrict__ ei, const int* __restrict__ wpip,
                      const int* __restrict__ inv, const float* __restrict__ esc,
                      float* __restrict__ outb) {
    int c = blockIdx.x * blockDim.x + threadIdx.x;
    if (c >= GE2) return;
    int wpi = *wpip;
    int s, dd;
    float av;
    if (c < GE) {
        s = gidx(ei, c, wpi);
        dd = gidx(ei, (long long)GE + c, wpi);
        av = esc[inv[c]];
    } else if (c < GE1) {
        s = dd = c - GE;
        av = esc[c];
    } else {
        s = dd = c - GE1;
        av = esc[c];
    }
    outb[G0 + c]       = (float)s;
    outb[G0 + GE2 + c] = (float)dd;
    outb[G1 + c]       = av;
}

extern "C" void kernel_launch(void* const* d_in, const int* in_sizes, int n_in,
                              void* d_out, int out_size, void* d_ws, size_t ws_size,
                              hipStream_t stream) {
    const float* x     = (const float*)d_in[0];
    const int*   ei    = (const int*)d_in[1];
    const float* eattr = (const float*)d_in[2];
    const float* W1l   = (const float*)d_in[3];
    const float* W1r   = (const float*)d_in[4];
    const float* W1e   = (const float*)d_in[5];
    const float* att1  = (const float*)d_in[6];
    const float* b1    = (const float*)d_in[7];
    const float* W2l   = (const float*)d_in[8];
    const float* W2r   = (const float*)d_in[9];
    const float* W2e   = (const float*)d_in[10];
    const float* att2  = (const float*)d_in[11];
    const float* b2    = (const float*)d_in[12];
    float* outf = (float*)d_out;

    float* ws = (float*)d_ws;
    if (W_END * sizeof(float) > ws_size) {          // 56.8 MB needed
        gl_sentinel<<<1, 64, 0, stream>>>(outf);
        return;
    }

    float*          esc  = ws + W_ESC;
    float*          lg   = ws + W_LG;
    unsigned short* xl1h = (unsigned short*)(ws + W_XL1H);
    float*          xr1  = ws + W_XR1;
    unsigned short* xl2h = (unsigned short*)(ws + W_XL2H);
    float*          xr2  = ws + W_XR2;
    int*            rp   = (int*)(ws + W_RP);
    int*            cnt  = (int*)(ws + W_CNT);
    int*            bs   = (int*)(ws + W_BS);
    float*          sea  = ws + W_SEA;
    int*            wpi  = (int*)(ws + W_WPI);

    int*   rank = (int*)(outf + G0);                // killed by pse after gl_slots
    int2*  pse  = (int2*)(outf + G0);               // ei2 region, killed by gl_ep
    int*   inv  = (int*)(outf + G1);                // a2 region, read-then-overwritten
    float* h1   = outf;                             // chunk0, killed by L2's out0

    hipMemsetAsync(cnt, 0, GN * sizeof(int), stream);
    hipMemsetAsync(sea, 0, 2 * sizeof(float), stream);

    gl_detect<<<1, 64, 0, stream>>>(ei, wpi);
    gl_sum<<<1024, 256, 0, stream>>>(eattr, GE, sea);
    gl_projA<<<GN / 16, 256, 0, stream>>>(x, W1l, W1r, xl1h, xr1);

    int nbe = (GE + 255) / 256;
    gl_hist<<<nbe, 256, 0, stream>>>(ei, wpi, cnt, rank);
    gl_scan1<<<(GN + 1023) / 1024, 1024, 0, stream>>>(cnt, rp, bs);
    gl_scan2<<<1, 128, 0, stream>>>(bs, (GN + 1023) / 1024);
    gl_scan3<<<(GN + 255) / 256, 256, 0, stream>>>(rp, bs);
    gl_slots<<<nbe, 256, 0, stream>>>(ei, wpi, rank, rp, inv);
    gl_scatter<<<8192, 256, 0, stream>>>(ei, wpi, eattr, inv, pse);

    gl_L1<<<GN / 4, 256, 0, stream>>>(rp, pse, sea, xl1h, xr1, W1e, att1, b1, esc, lg, h1);
    gl_projB<<<GN / 8, 256, 0, stream>>>(h1, W2l, W2r, xl2h, xr2);
    gl_L2<<<GN / 4, 256, 0, stream>>>(rp, pse, xl2h, xr2, W2e, att2, b2, esc, lg, outf);
    gl_ep<<<(GE2 + 255) / 256, 256, 0, stream>>>(ei, wpi, inv, esc, outf);
}

// Round 24
// 515.635 us; speedup vs baseline: 1.1712x; 1.0384x over previous
//
#include <hip/hip_runtime.h>

#define DEVFN __device__ __forceinline__

constexpr int GN = 100000, GE = 3200000;
constexpr int GE1 = GE + GN;          // 3,300,000
constexpr int GE2 = GE1 + GN;         // 3,400,000
constexpr int GEMB = 128, GHID = 16, GOUT = 32;
constexpr float GNEG = 0.2f;
constexpr float GEA2 = 100000.f / 3300000.f;   // mean(alpha1) = N/E1 exactly

constexpr long long G0 = (long long)GN * GOUT;   //  3,200,000  (out end)
constexpr long long G1 = G0 + 2LL * GE2;         // 10,000,000  (ei2 end; a2 follows)

constexpr unsigned CHUNK = 400000;    // pse slots per XCD-chunk

// front kernel block ranges: [hist | projA | sum]
constexpr int NB_HIST = (GE + 255) / 256;        // 12500
constexpr int NB_PROJ = GN / 16;                 // 6250
constexpr int NB_SUM  = 1024;

// ---- ws layout (floats), 56.8 MB ----
constexpr size_t W_ESC  = 0;          // GE2: alpha slots (self at GE+u, GE1+u)
constexpr size_t W_LG   = 3400000;    // GE2: logits
constexpr size_t W_XL1H = 6800000;    // N*HID bf16
constexpr size_t W_XR1  = 7600000;    // N*HID f32
constexpr size_t W_XL2H = 9200000;    // N*OUT bf16
constexpr size_t W_XR2  = 10800000;   // N*OUT f32
constexpr size_t W_RP   = 14000000;   // rowptr N+1 (int)
constexpr size_t W_CNT  = 14100004;   // cnt N (int)
constexpr size_t W_BS   = 14200004;   // scan block sums (256)
constexpr size_t W_SEA  = 14200260;
constexpr size_t W_WPI  = 14200261;
constexpr size_t W_END  = 14200264;

DEVFN int gidx(const int* __restrict__ ei, long long i, int wpi) {
    return ei[(size_t)i * (size_t)wpi];
}
DEVFN unsigned short f2b(float f) {               // f32 -> bf16 RNE
    unsigned u = __float_as_uint(f);
    unsigned r = ((u >> 16) & 1u) + 0x7fffu;
    return (unsigned short)((u + r) >> 16);
}
DEVFN float b2fl(unsigned u) { return __uint_as_float(u << 16); }
DEVFN float b2fh(unsigned u) { return __uint_as_float(u & 0xffff0000u); }

DEVFN float dot8(uint4 h, const float* xru, const float* we, const float* at,
                 float ea, float* xs) {
    float s = 0.f;
    unsigned w[4] = {h.x, h.y, h.z, h.w};
    #pragma unroll
    for (int q = 0; q < 4; ++q) {
        float xa = b2fl(w[q]), xb = b2fh(w[q]);
        float v;
        v = xa + xru[2 * q]     + ea * we[2 * q];     v = v > 0.f ? v : GNEG * v;
        s = fmaf(v, at[2 * q], s);
        v = xb + xru[2 * q + 1] + ea * we[2 * q + 1]; v = v > 0.f ? v : GNEG * v;
        s = fmaf(v, at[2 * q + 1], s);
        xs[2 * q] = xa; xs[2 * q + 1] = xb;
    }
    return s;
}

__global__ void gl_sentinel(float* outb) {        // ws too small -> Output 2 ~ 3840
    if (threadIdx.x == 0 && blockIdx.x == 0) outb[G1] = 3840.0f;
}

__global__ void gl_detect(const int* __restrict__ ei, int* flag) {
    int t = threadIdx.x;
    int v = ei[2 * t + 1];
    unsigned long long nz = __ballot(v != 0);
    if (t == 0) *flag = (nz == 0ull) ? 2 : 1;
}

// ---- fused front: [hist | projA | sum(eattr)] in one dispatch ----
__global__ __launch_bounds__(256) void gl_front(const int* __restrict__ ei,
        const int* __restrict__ wpip, int* __restrict__ cnt, int* __restrict__ rank,
        const float* __restrict__ x, const float* __restrict__ Wl,
        const float* __restrict__ Wr, unsigned short* __restrict__ xlh,
        float* __restrict__ xr, const float* __restrict__ eattr,
        float* __restrict__ sea) {
    int b = blockIdx.x;
    if (b < NB_HIST) {
        // ---- hist: 1 atomic per edge ----
        int e = b * 256 + threadIdx.x;
        if (e < GE) {
            int wpi = *wpip;
            int dst = gidx(ei, (long long)GE + e, wpi);
            rank[e] = atomicAdd(&cnt[dst], 1);
        }
        return;
    }
    if (b < NB_HIST + NB_PROJ) {
        // ---- projA: x @ {W1l,W1r} for 16 nodes ----
        __shared__ float sWl[GEMB * GHID], sWr[GEMB * GHID], sx[16 * GEMB];
        for (int i = threadIdx.x; i < GEMB * GHID; i += 256) { sWl[i] = Wl[i]; sWr[i] = Wr[i]; }
        int base = (b - NB_HIST) * 16;
        for (int i = threadIdx.x; i < 16 * GEMB; i += 256) sx[i] = x[(size_t)base * GEMB + i];
        __syncthreads();
        int ln = threadIdx.x >> 4, ch = threadIdx.x & 15;
        float al = 0.f, ar = 0.f;
        #pragma unroll 8
        for (int k = 0; k < GEMB; ++k) {
            float xv = sx[ln * GEMB + k];
            al = fmaf(xv, sWl[k * GHID + ch], al);
            ar = fmaf(xv, sWr[k * GHID + ch], ar);
        }
        xlh[(size_t)(base + ln) * GHID + ch] = f2b(al);
        xr[(size_t)(base + ln) * GHID + ch] = ar;
        return;
    }
    {   // ---- sum(eattr): grid-stride over NB_SUM blocks ----
        int sb = b - NB_HIST - NB_PROJ;
        float s = 0.f;
        for (int i = sb * 256 + threadIdx.x; i < GE; i += NB_SUM * 256)
            s += eattr[i];
        #pragma unroll
        for (int o = 32; o > 0; o >>= 1) s += __shfl_down(s, o);
        __shared__ float ls[4];
        if ((threadIdx.x & 63) == 0) ls[threadIdx.x >> 6] = s;
        __syncthreads();
        if (threadIdx.x == 0) atomicAdd(sea, ls[0] + ls[1] + ls[2] + ls[3]);
    }
}

__global__ __launch_bounds__(1024) void gl_scan1(const int* __restrict__ cnt,
                                                 int* __restrict__ rp, int* __restrict__ bs) {
    __shared__ int s[1024];
    int t = threadIdx.x, u = blockIdx.x * 1024 + t;
    s[t] = (u < GN) ? cnt[u] : 0;
    __syncthreads();
    for (int off = 1; off < 1024; off <<= 1) {
        int a = (t >= off) ? s[t - off] : 0;
        __syncthreads();
        s[t] += a;
        __syncthreads();
    }
    if (u < GN) rp[u + 1] = s[t];
    if (t == 1023) bs[blockIdx.x] = s[1023];
}
__global__ void gl_scan2(int* __restrict__ bs, int nb) {
    __shared__ int s[128];
    int t = threadIdx.x;
    s[t] = (t < nb) ? bs[t] : 0;
    __syncthreads();
    for (int off = 1; off < 128; off <<= 1) {
        int a = (t >= off) ? s[t - off] : 0;
        __syncthreads();
        s[t] += a;
        __syncthreads();
    }
    if (t < nb) bs[t] = (t == 0) ? 0 : s[t - 1];
}
__global__ void gl_scan3(int* __restrict__ rp, const int* __restrict__ bs) {
    int u = blockIdx.x * blockDim.x + threadIdx.x;
    if (u < GN) rp[u + 1] += bs[u >> 10];
    if (u == 0) rp[0] = 0;
}

__global__ void gl_slots(const int* __restrict__ ei, const int* __restrict__ wpip,
                         const int* __restrict__ rank, const int* __restrict__ rp,
                         int* __restrict__ inv) {
    int e = blockIdx.x * blockDim.x + threadIdx.x;
    if (e >= GE) return;
    int wpi = *wpip;
    int dst = gidx(ei, (long long)GE + e, wpi);
    inv[e] = rp[dst] + rank[e];
}

__global__ __launch_bounds__(256) void gl_scatter(const int* __restrict__ ei,
        const int* __restrict__ wpip, const float* __restrict__ eattr,
        const int* __restrict__ inv, int2* __restrict__ pse) {
    int wpi = *wpip;
    unsigned ck = blockIdx.x & 7;
    int stride = (gridDim.x >> 3) * 256;
    for (int e = (blockIdx.x >> 3) * 256 + threadIdx.x; e < GE; e += stride) {
        int slot = inv[e];
        if ((unsigned)slot / CHUNK == ck) {
            int src = gidx(ei, e, wpi);
            pse[slot] = make_int2(src, __float_as_int(eattr[e]));
        }
    }
}

__global__ __launch_bounds__(256) void gl_projB(const float* __restrict__ h,
        const float* __restrict__ Wl, const float* __restrict__ Wr,
        unsigned short* __restrict__ xlh, float* __restrict__ xr) {
    __shared__ float sWl[GHID * GOUT], sWr[GHID * GOUT], sx[8 * GHID];
    for (int i = threadIdx.x; i < GHID * GOUT; i += 256) { sWl[i] = Wl[i]; sWr[i] = Wr[i]; }
    int base = blockIdx.x * 8;
    for (int i = threadIdx.x; i < 8 * GHID; i += 256) sx[i] = h[(size_t)base * GHID + i];
    __syncthreads();
    int ln = threadIdx.x >> 5, ch = threadIdx.x & 31;
    float al = 0.f, ar = 0.f;
    #pragma unroll
    for (int k = 0; k < GHID; ++k) {
        float xv = sx[ln * GHID + k];
        al = fmaf(xv, sWl[k * GOUT + ch], al);
        ar = fmaf(xv, sWr[k * GOUT + ch], ar);
    }
    xlh[(size_t)(base + ln) * GOUT + ch] = f2b(al);
    xr[(size_t)(base + ln) * GOUT + ch] = ar;
}

// ------- layer 1: 2 lanes/edge (8ch), 32 edges in flight (HID=16) -------
__global__ __launch_bounds__(256) void gl_L1(const int* __restrict__ rp,
        const int2* __restrict__ pse, const float* __restrict__ sea,
        const unsigned short* __restrict__ xlh, const float* __restrict__ xr,
        const float* __restrict__ We, const float* __restrict__ att,
        const float* __restrict__ b1, float* __restrict__ esc,
        float* __restrict__ lg, float* __restrict__ h1) {
    int u = blockIdx.x * 4 + (threadIdx.x >> 6);
    int lane = threadIdx.x & 63, sg = lane >> 1, ln2 = lane & 1;
    int beg = rp[u], end = rp[u + 1];
    float we[8], at[8], xru[8];
    #pragma unroll
    for (int q = 0; q < 8; ++q) {
        we[q] = We[ln2 * 8 + q];
        at[q] = att[ln2 * 8 + q];
        xru[q] = xr[(size_t)u * GHID + ln2 * 8 + q];
    }
    float mx = -3.0e38f, pd = 0.f;
    float acc[8] = {0, 0, 0, 0, 0, 0, 0, 0};
    int i = beg + sg;
    int2 p = (i < end) ? pse[i] : make_int2(0, 0);
    uint4 h = (i < end) ? *(const uint4*)(xlh + (size_t)p.x * GHID + ln2 * 8)
                        : make_uint4(0, 0, 0, 0);
    for (; i < end; i += 32) {
        int inx = i + 32;
        int2 pn = (inx < end) ? pse[inx] : make_int2(0, 0);
        uint4 hn = (inx < end) ? *(const uint4*)(xlh + (size_t)pn.x * GHID + ln2 * 8)
                               : make_uint4(0, 0, 0, 0);
        float xs[8];
        float s = dot8(h, xru, we, at, __int_as_float(p.y), xs);
        s += __shfl_xor(s, 1);
        if (ln2 == 0) lg[i] = s;
        float nm = fmaxf(mx, s);
        float sc = __expf(mx - nm), pp = __expf(s - nm);
        pd = pd * sc + pp;
        #pragma unroll
        for (int q = 0; q < 8; ++q) acc[q] = acc[q] * sc + pp * xs[q];
        mx = nm;
        p = pn; h = hn;
    }
    float lgself = 0.f;
    if (sg == 0) {                                  // self-loop (ea = mean(edge_attr))
        uint4 hs = *(const uint4*)(xlh + (size_t)u * GHID + ln2 * 8);
        float xs[8];
        float s = dot8(hs, xru, we, at, sea[0] * (1.f / (float)GE), xs);
        s += __shfl_xor(s, 1);
        lgself = s;
        float nm = fmaxf(mx, s);
        float sc = __expf(mx - nm), pp = __expf(s - nm);
        pd = pd * sc + pp;
        #pragma unroll
        for (int q = 0; q < 8; ++q) acc[q] = acc[q] * sc + pp * xs[q];
        mx = nm;
    }
    #pragma unroll
    for (int o = 2; o <= 32; o <<= 1) {             // merge 32 subgroups
        float mo = __shfl_xor(mx, o), po = __shfl_xor(pd, o);
        float ao[8];
        #pragma unroll
        for (int q = 0; q < 8; ++q) ao[q] = __shfl_xor(acc[q], o);
        float nm = fmaxf(mx, mo);
        float sa = __expf(mx - nm), sb = __expf(mo - nm);
        pd = pd * sa + po * sb;
        #pragma unroll
        for (int q = 0; q < 8; ++q) acc[q] = acc[q] * sa + ao[q] * sb;
        mx = nm;
    }
    float dinv = 1.f / pd;
    __threadfence_block();
    for (int j = beg + lane; j < end; j += 64)      // alpha pass (coalesced)
        esc[j] = __expf(lg[j] - mx) * dinv;
    if (lane == 0) esc[GE + u] = __expf(lgself - mx) * dinv;
    if (lane < 2) {
        float o[8];
        #pragma unroll
        for (int q = 0; q < 8; ++q) {
            o[q] = acc[q] * dinv + b1[lane * 8 + q];
            o[q] = o[q] > 0.f ? o[q] : 0.f;         // fused bias+relu
        }
        *(float4*)(h1 + (size_t)u * GHID + lane * 8)     = make_float4(o[0], o[1], o[2], o[3]);
        *(float4*)(h1 + (size_t)u * GHID + lane * 8 + 4) = make_float4(o[4], o[5], o[6], o[7]);
    }
}

// ------- layer 2: 4 lanes/edge (8ch), 16 edges in flight (OUT=32) -------
__global__ __launch_bounds__(256) void gl_L2(const int* __restrict__ rp,
        const int2* __restrict__ pse,
        const unsigned short* __restrict__ xlh, const float* __restrict__ xr,
        const float* __restrict__ We, const float* __restrict__ att,
        const float* __restrict__ b2, float* __restrict__ esc,
        float* __restrict__ lg, float* __restrict__ out0) {
    int u = blockIdx.x * 4 + (threadIdx.x >> 6);
    int lane = threadIdx.x & 63, sg = lane >> 2, ln4 = lane & 3;
    int beg = rp[u], end = rp[u + 1];
    float we[8], at[8], xru[8];
    #pragma unroll
    for (int q = 0; q < 8; ++q) {
        we[q] = We[ln4 * 8 + q];
        at[q] = att[ln4 * 8 + q];
        xru[q] = xr[(size_t)u * GOUT + ln4 * 8 + q];
    }
    float mx = -3.0e38f, pd = 0.f;
    float acc[8] = {0, 0, 0, 0, 0, 0, 0, 0};
    int i = beg + sg;
    int2 p = (i < end) ? pse[i] : make_int2(0, 0);
    float ea = (i < end) ? esc[i] : 0.f;
    uint4 h = (i < end) ? *(const uint4*)(xlh + (size_t)p.x * GOUT + ln4 * 8)
                        : make_uint4(0, 0, 0, 0);
    for (; i < end; i += 16) {
        int inx = i + 16;
        int2 pn = (inx < end) ? pse[inx] : make_int2(0, 0);
        float ean = (inx < end) ? esc[inx] : 0.f;
        uint4 hn = (inx < end) ? *(const uint4*)(xlh + (size_t)pn.x * GOUT + ln4 * 8)
                               : make_uint4(0, 0, 0, 0);
        float xs[8];
        float s = dot8(h, xru, we, at, ea, xs);
        s += __shfl_xor(s, 1); s += __shfl_xor(s, 2);
        if (ln4 == 0) lg[i] = s;
        float nm = fmaxf(mx, s);
        float sc = __expf(mx - nm), pp = __expf(s - nm);
        pd = pd * sc + pp;
        #pragma unroll
        for (int q = 0; q < 8; ++q) acc[q] = acc[q] * sc + pp * xs[q];
        mx = nm;
        p = pn; ea = ean; h = hn;
    }
    float lgs = 0.f;
    if (sg < 2) {   // two self-loops: sg0 -> ea=alpha1_self, sg1 -> ea=N/E1
        float eas = (sg == 0) ? esc[GE + u] : GEA2;
        uint4 hs = *(const uint4*)(xlh + (size_t)u * GOUT + ln4 * 8);
        float xs[8];
        float s = dot8(hs, xru, we, at, eas, xs);
        s += __shfl_xor(s, 1); s += __shfl_xor(s, 2);
        lgs = s;
        float nm = fmaxf(mx, s);
        float sc = __expf(mx - nm), pp = __expf(s - nm);
        pd = pd * sc + pp;
        #pragma unroll
        for (int q = 0; q < 8; ++q) acc[q] = acc[q] * sc + pp * xs[q];
        mx = nm;
    }
    #pragma unroll
    for (int o = 4; o <= 32; o <<= 1) {             // merge 16 subgroups
        float mo = __shfl_xor(mx, o), po = __shfl_xor(pd, o);
        float ao[8];
        #pragma unroll
        for (int q = 0; q < 8; ++q) ao[q] = __shfl_xor(acc[q], o);
        float nm = fmaxf(mx, mo);
        float sa = __expf(mx - nm), sb = __expf(mo - nm);
        pd = pd * sa + po * sb;
        #pragma unroll
        for (int q = 0; q < 8; ++q) acc[q] = acc[q] * sa + ao[q] * sb;
        mx = nm;
    }
    float dinv = 1.f / pd;
    __threadfence_block();
    for (int j = beg + lane; j < end; j += 64)      // alpha2 pass (coalesced)
        esc[j] = __expf(lg[j] - mx) * dinv;
    if (lane == 0) esc[GE + u]  = __expf(lgs - mx) * dinv;
    if (lane == 4) esc[GE1 + u] = __expf(lgs - mx) * dinv;
    if (lane < 4) {
        float o[8];
        #pragma unroll
        for (int q = 0; q < 8; ++q) o[q] = acc[q] * dinv + b2[lane * 8 + q];
        *(float4*)(out0 + (size_t)u * GOUT + lane * 8)     = make_float4(o[0], o[1], o[2], o[3]);
        *(float4*)(out0 + (size_t)u * GOUT + lane * 8 + 4) = make_float4(o[4], o[5], o[6], o[7]);
    }
}

// fused epilogue
__global__ void gl_ep(const int* __restrict__ ei, const int* __restrict__ wpip,
                      const int* __restrict__ inv, const float* __restrict__ esc,
                      float* __restrict__ outb) {
    int c = blockIdx.x * blockDim.x + threadIdx.x;
    if (c >= GE2) return;
    int wpi = *wpip;
    int s, dd;
    float av;
    if (c < GE) {
        s = gidx(ei, c, wpi);
        dd = gidx(ei, (long long)GE + c, wpi);
        av = esc[inv[c]];
    } else if (c < GE1) {
        s = dd = c - GE;
        av = esc[c];
    } else {
        s = dd = c - GE1;
        av = esc[c];
    }
    outb[G0 + c]       = (float)s;
    outb[G0 + GE2 + c] = (float)dd;
    outb[G1 + c]       = av;
}

extern "C" void kernel_launch(void* const* d_in, const int* in_sizes, int n_in,
                              void* d_out, int out_size, void* d_ws, size_t ws_size,
                              hipStream_t stream) {
    const float* x     = (const float*)d_in[0];
    const int*   ei    = (const int*)d_in[1];
    const float* eattr = (const float*)d_in[2];
    const float* W1l   = (const float*)d_in[3];
    const float* W1r   = (const float*)d_in[4];
    const float* W1e   = (const float*)d_in[5];
    const float* att1  = (const float*)d_in[6];
    const float* b1    = (const float*)d_in[7];
    const float* W2l   = (const float*)d_in[8];
    const float* W2r   = (const float*)d_in[9];
    const float* W2e   = (const float*)d_in[10];
    const float* att2  = (const float*)d_in[11];
    const float* b2    = (const float*)d_in[12];
    float* outf = (float*)d_out;

    float* ws = (float*)d_ws;
    if (W_END * sizeof(float) > ws_size) {          // 56.8 MB needed
        gl_sentinel<<<1, 64, 0, stream>>>(outf);
        return;
    }

    float*          esc  = ws + W_ESC;
    float*          lg   = ws + W_LG;
    unsigned short* xl1h = (unsigned short*)(ws + W_XL1H);
    float*          xr1  = ws + W_XR1;
    unsigned short* xl2h = (unsigned short*)(ws + W_XL2H);
    float*          xr2  = ws + W_XR2;
    int*            rp   = (int*)(ws + W_RP);
    int*            cnt  = (int*)(ws + W_CNT);
    int*            bs   = (int*)(ws + W_BS);
    float*          sea  = ws + W_SEA;
    int*            wpi  = (int*)(ws + W_WPI);

    int*   rank = (int*)(outf + G0);                // killed by pse after gl_slots
    int2*  pse  = (int2*)(outf + G0);               // ei2 region, killed by gl_ep
    int*   inv  = (int*)(outf + G1);                // a2 region, read-then-overwritten
    float* h1   = outf;                             // chunk0, killed by L2's out0

    hipMemsetAsync(cnt, 0, GN * sizeof(int), stream);
    hipMemsetAsync(sea, 0, 2 * sizeof(float), stream);

    gl_detect<<<1, 64, 0, stream>>>(ei, wpi);
    gl_front<<<NB_HIST + NB_PROJ + NB_SUM, 256, 0, stream>>>(
        ei, wpi, cnt, rank, x, W1l, W1r, xl1h, xr1, eattr, sea);

    int nbe = (GE + 255) / 256;
    gl_scan1<<<(GN + 1023) / 1024, 1024, 0, stream>>>(cnt, rp, bs);
    gl_scan2<<<1, 128, 0, stream>>>(bs, (GN + 1023) / 1024);
    gl_scan3<<<(GN + 255) / 256, 256, 0, stream>>>(rp, bs);
    gl_slots<<<nbe, 256, 0, stream>>>(ei, wpi, rank, rp, inv);
    gl_scatter<<<8192, 256, 0, stream>>>(ei, wpi, eattr, inv, pse);

    gl_L1<<<GN / 4, 256, 0, stream>>>(rp, pse, sea, xl1h, xr1, W1e, att1, b1, esc, lg, h1);
    gl_projB<<<GN / 8, 256, 0, stream>>>(h1, W2l, W2r, xl2h, xr2);
    gl_L2<<<GN / 4, 256, 0, stream>>>(rp, pse, xl2h, xr2, W2e, att2, b2, esc, lg, outf);
    gl_ep<<<(GE2 + 255) / 256, 256, 0, stream>>>(ei, wpi, inv, esc, outf);
}

// Round 25
// 487.393 us; speedup vs baseline: 1.2391x; 1.0579x over previous
//
#include <hip/hip_runtime.h>

#define DEVFN __device__ __forceinline__

constexpr int GN = 100000, GE = 3200000;
constexpr int GE1 = GE + GN;          // 3,300,000
constexpr int GE2 = GE1 + GN;         // 3,400,000
constexpr int GEMB = 128, GHID = 16, GOUT = 32;
constexpr float GNEG = 0.2f;
constexpr float GEA2 = 100000.f / 3300000.f;   // mean(alpha1) = N/E1 exactly

constexpr long long G0 = (long long)GN * GOUT;   //  3,200,000  (out end)
constexpr long long G1 = G0 + 2LL * GE2;         // 10,000,000  (ei2 end; a2 follows)

constexpr unsigned CHUNK = 400000;    // pse slots per XCD-chunk

// front kernel: 2:1 interleave of [hist | projA], sum appended
constexpr int NB_HIST = (GE + 255) / 256;        // 12500
constexpr int NB_PROJ = GN / 16;                 // 6250
constexpr int NB_MIX  = NB_HIST + NB_PROJ;       // 18750 (multiple of 3)
constexpr int NB_SUM  = 1024;

// ---- ws layout (floats), 56.8 MB ----
constexpr size_t W_ESC  = 0;          // GE2: alpha slots (self at GE+u, GE1+u)
constexpr size_t W_LG   = 3400000;    // GE2: logits
constexpr size_t W_XL1H = 6800000;    // N*HID bf16
constexpr size_t W_XR1  = 7600000;    // N*HID f32
constexpr size_t W_XL2H = 9200000;    // N*OUT bf16
constexpr size_t W_XR2  = 10800000;   // N*OUT f32
constexpr size_t W_RP   = 14000000;   // rowptr N+1 (int)
constexpr size_t W_CNT  = 14100004;   // cnt N (int)
constexpr size_t W_BS   = 14200004;   // scan block sums (256)
constexpr size_t W_SEA  = 14200260;
constexpr size_t W_WPI  = 14200261;
constexpr size_t W_END  = 14200264;

DEVFN int gidx(const int* __restrict__ ei, long long i, int wpi) {
    return ei[(size_t)i * (size_t)wpi];
}
DEVFN unsigned short f2b(float f) {               // f32 -> bf16 RNE
    unsigned u = __float_as_uint(f);
    unsigned r = ((u >> 16) & 1u) + 0x7fffu;
    return (unsigned short)((u + r) >> 16);
}
DEVFN float b2fl(unsigned u) { return __uint_as_float(u << 16); }
DEVFN float b2fh(unsigned u) { return __uint_as_float(u & 0xffff0000u); }

DEVFN float dot8(uint4 h, const float* xru, const float* we, const float* at,
                 float ea, float* xs) {
    float s = 0.f;
    unsigned w[4] = {h.x, h.y, h.z, h.w};
    #pragma unroll
    for (int q = 0; q < 4; ++q) {
        float xa = b2fl(w[q]), xb = b2fh(w[q]);
        float v;
        v = xa + xru[2 * q]     + ea * we[2 * q];     v = v > 0.f ? v : GNEG * v;
        s = fmaf(v, at[2 * q], s);
        v = xb + xru[2 * q + 1] + ea * we[2 * q + 1]; v = v > 0.f ? v : GNEG * v;
        s = fmaf(v, at[2 * q + 1], s);
        xs[2 * q] = xa; xs[2 * q + 1] = xb;
    }
    return s;
}

__global__ void gl_sentinel(float* outb) {        // ws too small -> Output 2 ~ 3840
    if (threadIdx.x == 0 && blockIdx.x == 0) outb[G1] = 3840.0f;
}

__global__ void gl_detect(const int* __restrict__ ei, int* flag) {
    int t = threadIdx.x;
    int v = ei[2 * t + 1];
    unsigned long long nz = __ballot(v != 0);
    if (t == 0) *flag = (nz == 0ull) ? 2 : 1;
}

// ---- fused front: interleaved [hist | projA] + trailing sum(eattr) ----
__global__ __launch_bounds__(256) void gl_front(const int* __restrict__ ei,
        const int* __restrict__ wpip, int* __restrict__ cnt, int* __restrict__ rank,
        const float* __restrict__ x, const float* __restrict__ Wl,
        const float* __restrict__ Wr, unsigned short* __restrict__ xlh,
        float* __restrict__ xr, const float* __restrict__ eattr,
        float* __restrict__ sea) {
    __shared__ float sWl[GEMB * GHID], sWr[GEMB * GHID];   // 16.4 KB (proj only)
    int b = blockIdx.x;
    if (b < NB_MIX) {
        int r = b % 3, q = b / 3;
        if (r < 2) {
            // ---- hist: 1 atomic per edge ----
            int e = (q * 2 + r) * 256 + threadIdx.x;
            if (e < GE) {
                int wpi = *wpip;
                int dst = gidx(ei, (long long)GE + e, wpi);
                rank[e] = atomicAdd(&cnt[dst], 1);
            }
            return;
        }
        // ---- projA for 16 nodes; x read via lane-broadcast (no LDS staging) ----
        for (int i = threadIdx.x; i < GEMB * GHID; i += 256) { sWl[i] = Wl[i]; sWr[i] = Wr[i]; }
        __syncthreads();
        int base = q * 16;
        int ln = threadIdx.x >> 4, ch = threadIdx.x & 15;
        const float* xrow = x + (size_t)(base + ln) * GEMB;
        float al = 0.f, ar = 0.f;
        #pragma unroll 8
        for (int k = 0; k < GEMB; ++k) {
            float xv = xrow[k];                     // 16 lanes same addr -> broadcast
            al = fmaf(xv, sWl[k * GHID + ch], al);
            ar = fmaf(xv, sWr[k * GHID + ch], ar);
        }
        xlh[(size_t)(base + ln) * GHID + ch] = f2b(al);
        xr[(size_t)(base + ln) * GHID + ch] = ar;
        return;
    }
    {   // ---- sum(eattr): grid-stride over NB_SUM blocks ----
        int sb = b - NB_MIX;
        float s = 0.f;
        for (int i = sb * 256 + threadIdx.x; i < GE; i += NB_SUM * 256)
            s += eattr[i];
        #pragma unroll
        for (int o = 32; o > 0; o >>= 1) s += __shfl_down(s, o);
        __shared__ float ls[4];
        if ((threadIdx.x & 63) == 0) ls[threadIdx.x >> 6] = s;
        __syncthreads();
        if (threadIdx.x == 0) atomicAdd(sea, ls[0] + ls[1] + ls[2] + ls[3]);
    }
}

__global__ __launch_bounds__(1024) void gl_scan1(const int* __restrict__ cnt,
                                                 int* __restrict__ rp, int* __restrict__ bs) {
    __shared__ int s[1024];
    int t = threadIdx.x, u = blockIdx.x * 1024 + t;
    s[t] = (u < GN) ? cnt[u] : 0;
    __syncthreads();
    for (int off = 1; off < 1024; off <<= 1) {
        int a = (t >= off) ? s[t - off] : 0;
        __syncthreads();
        s[t] += a;
        __syncthreads();
    }
    if (u < GN) rp[u + 1] = s[t];
    if (t == 1023) bs[blockIdx.x] = s[1023];
}
__global__ void gl_scan2(int* __restrict__ bs, int nb) {
    __shared__ int s[128];
    int t = threadIdx.x;
    s[t] = (t < nb) ? bs[t] : 0;
    __syncthreads();
    for (int off = 1; off < 128; off <<= 1) {
        int a = (t >= off) ? s[t - off] : 0;
        __syncthreads();
        s[t] += a;
        __syncthreads();
    }
    if (t < nb) bs[t] = (t == 0) ? 0 : s[t - 1];
}
__global__ void gl_scan3(int* __restrict__ rp, const int* __restrict__ bs) {
    int u = blockIdx.x * blockDim.x + threadIdx.x;
    if (u < GN) rp[u + 1] += bs[u >> 10];
    if (u == 0) rp[0] = 0;
}

__global__ void gl_slots(const int* __restrict__ ei, const int* __restrict__ wpip,
                         const int* __restrict__ rank, const int* __restrict__ rp,
                         int* __restrict__ inv) {
    int e = blockIdx.x * blockDim.x + threadIdx.x;
    if (e >= GE) return;
    int wpi = *wpip;
    int dst = gidx(ei, (long long)GE + e, wpi);
    inv[e] = rp[dst] + rank[e];
}

__global__ __launch_bounds__(256) void gl_scatter(const int* __restrict__ ei,
        const int* __restrict__ wpip, const float* __restrict__ eattr,
        const int* __restrict__ inv, int2* __restrict__ pse) {
    int wpi = *wpip;
    unsigned ck = blockIdx.x & 7;
    int stride = (gridDim.x >> 3) * 256;
    for (int e = (blockIdx.x >> 3) * 256 + threadIdx.x; e < GE; e += stride) {
        int slot = inv[e];
        if ((unsigned)slot / CHUNK == ck) {
            int src = gidx(ei, e, wpi);
            pse[slot] = make_int2(src, __float_as_int(eattr[e]));
        }
    }
}

__global__ __launch_bounds__(256) void gl_projB(const float* __restrict__ h,
        const float* __restrict__ Wl, const float* __restrict__ Wr,
        unsigned short* __restrict__ xlh, float* __restrict__ xr) {
    __shared__ float sWl[GHID * GOUT], sWr[GHID * GOUT], sx[8 * GHID];
    for (int i = threadIdx.x; i < GHID * GOUT; i += 256) { sWl[i] = Wl[i]; sWr[i] = Wr[i]; }
    int base = blockIdx.x * 8;
    for (int i = threadIdx.x; i < 8 * GHID; i += 256) sx[i] = h[(size_t)base * GHID + i];
    __syncthreads();
    int ln = threadIdx.x >> 5, ch = threadIdx.x & 31;
    float al = 0.f, ar = 0.f;
    #pragma unroll
    for (int k = 0; k < GHID; ++k) {
        float xv = sx[ln * GHID + k];
        al = fmaf(xv, sWl[k * GOUT + ch], al);
        ar = fmaf(xv, sWr[k * GOUT + ch], ar);
    }
    xlh[(size_t)(base + ln) * GOUT + ch] = f2b(al);
    xr[(size_t)(base + ln) * GOUT + ch] = ar;
}

// ------- layer 1: 2 lanes/edge (8ch), 32 edges in flight (HID=16) -------
__global__ __launch_bounds__(256) void gl_L1(const int* __restrict__ rp,
        const int2* __restrict__ pse, const float* __restrict__ sea,
        const unsigned short* __restrict__ xlh, const float* __restrict__ xr,
        const float* __restrict__ We, const float* __restrict__ att,
        const float* __restrict__ b1, float* __restrict__ esc,
        float* __restrict__ lg, float* __restrict__ h1) {
    int u = blockIdx.x * 4 + (threadIdx.x >> 6);
    int lane = threadIdx.x & 63, sg = lane >> 1, ln2 = lane & 1;
    int beg = rp[u], end = rp[u + 1];
    float we[8], at[8], xru[8];
    #pragma unroll
    for (int q = 0; q < 8; ++q) {
        we[q] = We[ln2 * 8 + q];
        at[q] = att[ln2 * 8 + q];
        xru[q] = xr[(size_t)u * GHID + ln2 * 8 + q];
    }
    float mx = -3.0e38f, pd = 0.f;
    float acc[8] = {0, 0, 0, 0, 0, 0, 0, 0};
    int i = beg + sg;
    int2 p = (i < end) ? pse[i] : make_int2(0, 0);
    uint4 h = (i < end) ? *(const uint4*)(xlh + (size_t)p.x * GHID + ln2 * 8)
                        : make_uint4(0, 0, 0, 0);
    for (; i < end; i += 32) {
        int inx = i + 32;
        int2 pn = (inx < end) ? pse[inx] : make_int2(0, 0);
        uint4 hn = (inx < end) ? *(const uint4*)(xlh + (size_t)pn.x * GHID + ln2 * 8)
                               : make_uint4(0, 0, 0, 0);
        float xs[8];
        float s = dot8(h, xru, we, at, __int_as_float(p.y), xs);
        s += __shfl_xor(s, 1);
        if (ln2 == 0) lg[i] = s;
        float nm = fmaxf(mx, s);
        float sc = __expf(mx - nm), pp = __expf(s - nm);
        pd = pd * sc + pp;
        #pragma unroll
        for (int q = 0; q < 8; ++q) acc[q] = acc[q] * sc + pp * xs[q];
        mx = nm;
        p = pn; h = hn;
    }
    float lgself = 0.f;
    if (sg == 0) {                                  // self-loop (ea = mean(edge_attr))
        uint4 hs = *(const uint4*)(xlh + (size_t)u * GHID + ln2 * 8);
        float xs[8];
        float s = dot8(hs, xru, we, at, sea[0] * (1.f / (float)GE), xs);
        s += __shfl_xor(s, 1);
        lgself = s;
        float nm = fmaxf(mx, s);
        float sc = __expf(mx - nm), pp = __expf(s - nm);
        pd = pd * sc + pp;
        #pragma unroll
        for (int q = 0; q < 8; ++q) acc[q] = acc[q] * sc + pp * xs[q];
        mx = nm;
    }
    #pragma unroll
    for (int o = 2; o <= 32; o <<= 1) {             // merge 32 subgroups
        float mo = __shfl_xor(mx, o), po = __shfl_xor(pd, o);
        float ao[8];
        #pragma unroll
        for (int q = 0; q < 8; ++q) ao[q] = __shfl_xor(acc[q], o);
        float nm = fmaxf(mx, mo);
        float sa = __expf(mx - nm), sb = __expf(mo - nm);
        pd = pd * sa + po * sb;
        #pragma unroll
        for (int q = 0; q < 8; ++q) acc[q] = acc[q] * sa + ao[q] * sb;
        mx = nm;
    }
    float dinv = 1.f / pd;
    __threadfence_block();
    for (int j = beg + lane; j < end; j += 64)      // alpha pass (coalesced)
        esc[j] = __expf(lg[j] - mx) * dinv;
    if (lane == 0) esc[GE + u] = __expf(lgself - mx) * dinv;
    if (lane < 2) {
        float o[8];
        #pragma unroll
        for (int q = 0; q < 8; ++q) {
            o[q] = acc[q] * dinv + b1[lane * 8 + q];
            o[q] = o[q] > 0.f ? o[q] : 0.f;         // fused bias+relu
        }
        *(float4*)(h1 + (size_t)u * GHID + lane * 8)     = make_float4(o[0], o[1], o[2], o[3]);
        *(float4*)(h1 + (size_t)u * GHID + lane * 8 + 4) = make_float4(o[4], o[5], o[6], o[7]);
    }
}

// ------- layer 2: 4 lanes/edge (8ch), 16 edges in flight (OUT=32) -------
__global__ __launch_bounds__(256) void gl_L2(const int* __restrict__ rp,
        const int2* __restrict__ pse,
        const unsigned short* __restrict__ xlh, const float* __restrict__ xr,
        const float* __restrict__ We, const float* __restrict__ att,
        const float* __restrict__ b2, float* __restrict__ esc,
        float* __restrict__ lg, float* __restrict__ out0) {
    int u = blockIdx.x * 4 + (threadIdx.x >> 6);
    int lane = threadIdx.x & 63, sg = lane >> 2, ln4 = lane & 3;
    int beg = rp[u], end = rp[u + 1];
    float we[8], at[8], xru[8];
    #pragma unroll
    for (int q = 0; q < 8; ++q) {
        we[q] = We[ln4 * 8 + q];
        at[q] = att[ln4 * 8 + q];
        xru[q] = xr[(size_t)u * GOUT + ln4 * 8 + q];
    }
    float mx = -3.0e38f, pd = 0.f;
    float acc[8] = {0, 0, 0, 0, 0, 0, 0, 0};
    int i = beg + sg;
    int2 p = (i < end) ? pse[i] : make_int2(0, 0);
    float ea = (i < end) ? esc[i] : 0.f;
    uint4 h = (i < end) ? *(const uint4*)(xlh + (size_t)p.x * GOUT + ln4 * 8)
                        : make_uint4(0, 0, 0, 0);
    for (; i < end; i += 16) {
        int inx = i + 16;
        int2 pn = (inx < end) ? pse[inx] : make_int2(0, 0);
        float ean = (inx < end) ? esc[inx] : 0.f;
        uint4 hn = (inx < end) ? *(const uint4*)(xlh + (size_t)pn.x * GOUT + ln4 * 8)
                               : make_uint4(0, 0, 0, 0);
        float xs[8];
        float s = dot8(h, xru, we, at, ea, xs);
        s += __shfl_xor(s, 1); s += __shfl_xor(s, 2);
        if (ln4 == 0) lg[i] = s;
        float nm = fmaxf(mx, s);
        float sc = __expf(mx - nm), pp = __expf(s - nm);
        pd = pd * sc + pp;
        #pragma unroll
        for (int q = 0; q < 8; ++q) acc[q] = acc[q] * sc + pp * xs[q];
        mx = nm;
        p = pn; ea = ean; h = hn;
    }
    float lgs = 0.f;
    if (sg < 2) {   // two self-loops: sg0 -> ea=alpha1_self, sg1 -> ea=N/E1
        float eas = (sg == 0) ? esc[GE + u] : GEA2;
        uint4 hs = *(const uint4*)(xlh + (size_t)u * GOUT + ln4 * 8);
        float xs[8];
        float s = dot8(hs, xru, we, at, eas, xs);
        s += __shfl_xor(s, 1); s += __shfl_xor(s, 2);
        lgs = s;
        float nm = fmaxf(mx, s);
        float sc = __expf(mx - nm), pp = __expf(s - nm);
        pd = pd * sc + pp;
        #pragma unroll
        for (int q = 0; q < 8; ++q) acc[q] = acc[q] * sc + pp * xs[q];
        mx = nm;
    }
    #pragma unroll
    for (int o = 4; o <= 32; o <<= 1) {             // merge 16 subgroups
        float mo = __shfl_xor(mx, o), po = __shfl_xor(pd, o);
        float ao[8];
        #pragma unroll
        for (int q = 0; q < 8; ++q) ao[q] = __shfl_xor(acc[q], o);
        float nm = fmaxf(mx, mo);
        float sa = __expf(mx - nm), sb = __expf(mo - nm);
        pd = pd * sa + po * sb;
        #pragma unroll
        for (int q = 0; q < 8; ++q) acc[q] = acc[q] * sa + ao[q] * sb;
        mx = nm;
    }
    float dinv = 1.f / pd;
    __threadfence_block();
    for (int j = beg + lane; j < end; j += 64)      // alpha2 pass (coalesced)
        esc[j] = __expf(lg[j] - mx) * dinv;
    if (lane == 0) esc[GE + u]  = __expf(lgs - mx) * dinv;
    if (lane == 4) esc[GE1 + u] = __expf(lgs - mx) * dinv;
    if (lane < 4) {
        float o[8];
        #pragma unroll
        for (int q = 0; q < 8; ++q) o[q] = acc[q] * dinv + b2[lane * 8 + q];
        *(float4*)(out0 + (size_t)u * GOUT + lane * 8)     = make_float4(o[0], o[1], o[2], o[3]);
        *(float4*)(out0 + (size_t)u * GOUT + lane * 8 + 4) = make_float4(o[4], o[5], o[6], o[7]);
    }
}

// fused epilogue
__global__ void gl_ep(const int* __restrict__ ei, const int* __restrict__ wpip,
                      const int* __restrict__ inv, const float* __restrict__ esc,
                      float* __restrict__ outb) {
    int c = blockIdx.x * blockDim.x + threadIdx.x;
    if (c >= GE2) return;
    int wpi = *wpip;
    int s, dd;
    float av;
    if (c < GE) {
        s = gidx(ei, c, wpi);
        dd = gidx(ei, (long long)GE + c, wpi);
        av = esc[inv[c]];
    } else if (c < GE1) {
        s = dd = c - GE;
        av = esc[c];
    } else {
        s = dd = c - GE1;
        av = esc[c];
    }
    outb[G0 + c]       = (float)s;
    outb[G0 + GE2 + c] = (float)dd;
    outb[G1 + c]       = av;
}

extern "C" void kernel_launch(void* const* d_in, const int* in_sizes, int n_in,
                              void* d_out, int out_size, void* d_ws, size_t ws_size,
                              hipStream_t stream) {
    const float* x     = (const float*)d_in[0];
    const int*   ei    = (const int*)d_in[1];
    const float* eattr = (const float*)d_in[2];
    const float* W1l   = (const float*)d_in[3];
    const float* W1r   = (const float*)d_in[4];
    const float* W1e   = (const float*)d_in[5];
    const float* att1  = (const float*)d_in[6];
    const float* b1    = (const float*)d_in[7];
    const float* W2l   = (const float*)d_in[8];
    const float* W2r   = (const float*)d_in[9];
    const float* W2e   = (const float*)d_in[10];
    const float* att2  = (const float*)d_in[11];
    const float* b2    = (const float*)d_in[12];
    float* outf = (float*)d_out;

    float* ws = (float*)d_ws;
    if (W_END * sizeof(float) > ws_size) {          // 56.8 MB needed
        gl_sentinel<<<1, 64, 0, stream>>>(outf);
        return;
    }

    float*          esc  = ws + W_ESC;
    float*          lg   = ws + W_LG;
    unsigned short* xl1h = (unsigned short*)(ws + W_XL1H);
    float*          xr1  = ws + W_XR1;
    unsigned short* xl2h = (unsigned short*)(ws + W_XL2H);
    float*          xr2  = ws + W_XR2;
    int*            rp   = (int*)(ws + W_RP);
    int*            cnt  = (int*)(ws + W_CNT);
    int*            bs   = (int*)(ws + W_BS);
    float*          sea  = ws + W_SEA;
    int*            wpi  = (int*)(ws + W_WPI);

    int*   rank = (int*)(outf + G0);                // killed by pse after gl_slots
    int2*  pse  = (int2*)(outf + G0);               // ei2 region, killed by gl_ep
    int*   inv  = (int*)(outf + G1);                // a2 region, read-then-overwritten
    float* h1   = outf;                             // chunk0, killed by L2's out0

    hipMemsetAsync(cnt, 0, GN * sizeof(int), stream);
    hipMemsetAsync(sea, 0, 2 * sizeof(float), stream);

    gl_detect<<<1, 64, 0, stream>>>(ei, wpi);
    gl_front<<<NB_MIX + NB_SUM, 256, 0, stream>>>(
        ei, wpi, cnt, rank, x, W1l, W1r, xl1h, xr1, eattr, sea);

    int nbe = (GE + 255) / 256;
    gl_scan1<<<(GN + 1023) / 1024, 1024, 0, stream>>>(cnt, rp, bs);
    gl_scan2<<<1, 128, 0, stream>>>(bs, (GN + 1023) / 1024);
    gl_scan3<<<(GN + 255) / 256, 256, 0, stream>>>(rp, bs);
    gl_slots<<<nbe, 256, 0, stream>>>(ei, wpi, rank, rp, inv);
    gl_scatter<<<8192, 256, 0, stream>>>(ei, wpi, eattr, inv, pse);

    gl_L1<<<GN / 4, 256, 0, stream>>>(rp, pse, sea, xl1h, xr1, W1e, att1, b1, esc, lg, h1);
    gl_projB<<<GN / 8, 256, 0, stream>>>(h1, W2l, W2r, xl2h, xr2);
    gl_L2<<<GN / 4, 256, 0, stream>>>(rp, pse, xl2h, xr2, W2e, att2, b2, esc, lg, outf);
    gl_ep<<<(GE2 + 255) / 256, 256, 0, stream>>>(ei, wpi, inv, esc, outf);
}

// Round 26
// 485.272 us; speedup vs baseline: 1.2445x; 1.0044x over previous
//
#include <hip/hip_runtime.h>

#define DEVFN __device__ __forceinline__

constexpr int GN = 100000, GE = 3200000;
constexpr int GE1 = GE + GN;          // 3,300,000
constexpr int GE2 = GE1 + GN;         // 3,400,000
constexpr int GEMB = 128, GHID = 16, GOUT = 32;
constexpr float GNEG = 0.2f;
constexpr float GEA2 = 100000.f / 3300000.f;   // mean(alpha1) = N/E1 exactly

constexpr long long G0 = (long long)GN * GOUT;   //  3,200,000  (out end)
constexpr long long G1 = G0 + 2LL * GE2;         // 10,000,000  (ei2 end; a2 follows)

constexpr unsigned CHUNK = 400000;    // pse slots per XCD-chunk

// front kernel: 2:1 interleave of [hist | projA], sum appended
constexpr int NB_HIST = (GE + 255) / 256;        // 12500
constexpr int NB_PROJ = GN / 16;                 // 6250
constexpr int NB_MIX  = NB_HIST + NB_PROJ;       // 18750 (multiple of 3)
constexpr int NB_SUM  = 1024;

// L2big: interleaved [ei2-writer | L2] blocks
constexpr int NB_EI2 = (GE2 + 255) / 256;        // 13282
constexpr int NB_L2  = GN / 4;                   // 25000
constexpr int NB_L2BIG = 3 * 13282;              // 39846 (r==0 -> ei2, r>0 -> L2)

// ---- ws layout (floats): small = 56.8 MB, big adds pse = 82.4 MB ----
constexpr size_t W_ESC  = 0;
constexpr size_t W_LG   = 3400000;
constexpr size_t W_XL1H = 6800000;
constexpr size_t W_XR1  = 7600000;
constexpr size_t W_XL2H = 9200000;
constexpr size_t W_XR2  = 10800000;
constexpr size_t W_RP   = 14000000;
constexpr size_t W_CNT  = 14100004;
constexpr size_t W_BS   = 14200004;
constexpr size_t W_SEA  = 14200260;
constexpr size_t W_WPI  = 14200261;
constexpr size_t W_END  = 14200264;   // small-path requirement
constexpr size_t W_PSE  = 14200272;   // 16B-aligned; 2*GE floats
constexpr size_t W_ENDB = W_PSE + 2 * (size_t)GE;   // 20,600,272 floats = 82.4 MB

DEVFN int gidx(const int* __restrict__ ei, long long i, int wpi) {
    return ei[(size_t)i * (size_t)wpi];
}
DEVFN unsigned short f2b(float f) {               // f32 -> bf16 RNE
    unsigned u = __float_as_uint(f);
    unsigned r = ((u >> 16) & 1u) + 0x7fffu;
    return (unsigned short)((u + r) >> 16);
}
DEVFN float b2fl(unsigned u) { return __uint_as_float(u << 16); }
DEVFN float b2fh(unsigned u) { return __uint_as_float(u & 0xffff0000u); }

DEVFN float dot8(uint4 h, const float* xru, const float* we, const float* at,
                 float ea, float* xs) {
    float s = 0.f;
    unsigned w[4] = {h.x, h.y, h.z, h.w};
    #pragma unroll
    for (int q = 0; q < 4; ++q) {
        float xa = b2fl(w[q]), xb = b2fh(w[q]);
        float v;
        v = xa + xru[2 * q]     + ea * we[2 * q];     v = v > 0.f ? v : GNEG * v;
        s = fmaf(v, at[2 * q], s);
        v = xb + xru[2 * q + 1] + ea * we[2 * q + 1]; v = v > 0.f ? v : GNEG * v;
        s = fmaf(v, at[2 * q + 1], s);
        xs[2 * q] = xa; xs[2 * q + 1] = xb;
    }
    return s;
}

__global__ void gl_sentinel(float* outb) {        // ws too small -> Output 2 ~ 3840
    if (threadIdx.x == 0 && blockIdx.x == 0) outb[G1] = 3840.0f;
}

__global__ void gl_detect(const int* __restrict__ ei, int* flag) {
    int t = threadIdx.x;
    int v = ei[2 * t + 1];
    unsigned long long nz = __ballot(v != 0);
    if (t == 0) *flag = (nz == 0ull) ? 2 : 1;
}

// ---- fused front: interleaved [hist | projA] + trailing sum(eattr) ----
__global__ __launch_bounds__(256) void gl_front(const int* __restrict__ ei,
        const int* __restrict__ wpip, int* __restrict__ cnt, int* __restrict__ rank,
        const float* __restrict__ x, const float* __restrict__ Wl,
        const float* __restrict__ Wr, unsigned short* __restrict__ xlh,
        float* __restrict__ xr, const float* __restrict__ eattr,
        float* __restrict__ sea) {
    __shared__ float sWl[GEMB * GHID], sWr[GEMB * GHID];   // 16.4 KB
    int b = blockIdx.x;
    if (b < NB_MIX) {
        int r = b % 3, q = b / 3;
        if (r < 2) {
            int e = (q * 2 + r) * 256 + threadIdx.x;
            if (e < GE) {
                int wpi = *wpip;
                int dst = gidx(ei, (long long)GE + e, wpi);
                rank[e] = atomicAdd(&cnt[dst], 1);
            }
            return;
        }
        for (int i = threadIdx.x; i < GEMB * GHID; i += 256) { sWl[i] = Wl[i]; sWr[i] = Wr[i]; }
        __syncthreads();
        int base = q * 16;
        int ln = threadIdx.x >> 4, ch = threadIdx.x & 15;
        const float* xrow = x + (size_t)(base + ln) * GEMB;
        float al = 0.f, ar = 0.f;
        #pragma unroll 8
        for (int k = 0; k < GEMB; ++k) {
            float xv = xrow[k];
            al = fmaf(xv, sWl[k * GHID + ch], al);
            ar = fmaf(xv, sWr[k * GHID + ch], ar);
        }
        xlh[(size_t)(base + ln) * GHID + ch] = f2b(al);
        xr[(size_t)(base + ln) * GHID + ch] = ar;
        return;
    }
    {
        int sb = b - NB_MIX;
        float s = 0.f;
        for (int i = sb * 256 + threadIdx.x; i < GE; i += NB_SUM * 256)
            s += eattr[i];
        #pragma unroll
        for (int o = 32; o > 0; o >>= 1) s += __shfl_down(s, o);
        __shared__ float ls[4];
        if ((threadIdx.x & 63) == 0) ls[threadIdx.x >> 6] = s;
        __syncthreads();
        if (threadIdx.x == 0) atomicAdd(sea, ls[0] + ls[1] + ls[2] + ls[3]);
    }
}

__global__ __launch_bounds__(1024) void gl_scan1(const int* __restrict__ cnt,
                                                 int* __restrict__ rp, int* __restrict__ bs) {
    __shared__ int s[1024];
    int t = threadIdx.x, u = blockIdx.x * 1024 + t;
    s[t] = (u < GN) ? cnt[u] : 0;
    __syncthreads();
    for (int off = 1; off < 1024; off <<= 1) {
        int a = (t >= off) ? s[t - off] : 0;
        __syncthreads();
        s[t] += a;
        __syncthreads();
    }
    if (u < GN) rp[u + 1] = s[t];
    if (t == 1023) bs[blockIdx.x] = s[1023];
}
__global__ void gl_scan2(int* __restrict__ bs, int nb) {
    __shared__ int s[128];
    int t = threadIdx.x;
    s[t] = (t < nb) ? bs[t] : 0;
    __syncthreads();
    for (int off = 1; off < 128; off <<= 1) {
        int a = (t >= off) ? s[t - off] : 0;
        __syncthreads();
        s[t] += a;
        __syncthreads();
    }
    if (t < nb) bs[t] = (t == 0) ? 0 : s[t - 1];
}
__global__ void gl_scan3(int* __restrict__ rp, const int* __restrict__ bs) {
    int u = blockIdx.x * blockDim.x + threadIdx.x;
    if (u < GN) rp[u + 1] += bs[u >> 10];
    if (u == 0) rp[0] = 0;
}

__global__ void gl_slots(const int* __restrict__ ei, const int* __restrict__ wpip,
                         const int* __restrict__ rank, const int* __restrict__ rp,
                         int* __restrict__ inv) {
    int e = blockIdx.x * blockDim.x + threadIdx.x;
    if (e >= GE) return;
    int wpi = *wpip;
    int dst = gidx(ei, (long long)GE + e, wpi);
    inv[e] = rp[dst] + rank[e];
}

__global__ __launch_bounds__(256) void gl_scatter(const int* __restrict__ ei,
        const int* __restrict__ wpip, const float* __restrict__ eattr,
        const int* __restrict__ inv, int2* __restrict__ pse) {
    int wpi = *wpip;
    unsigned ck = blockIdx.x & 7;
    int stride = (gridDim.x >> 3) * 256;
    for (int e = (blockIdx.x >> 3) * 256 + threadIdx.x; e < GE; e += stride) {
        int slot = inv[e];
        if ((unsigned)slot / CHUNK == ck) {
            int src = gidx(ei, e, wpi);
            pse[slot] = make_int2(src, __float_as_int(eattr[e]));
        }
    }
}

__global__ __launch_bounds__(256) void gl_projB(const float* __restrict__ h,
        const float* __restrict__ Wl, const float* __restrict__ Wr,
        unsigned short* __restrict__ xlh, float* __restrict__ xr) {
    __shared__ float sWl[GHID * GOUT], sWr[GHID * GOUT], sx[8 * GHID];
    for (int i = threadIdx.x; i < GHID * GOUT; i += 256) { sWl[i] = Wl[i]; sWr[i] = Wr[i]; }
    int base = blockIdx.x * 8;
    for (int i = threadIdx.x; i < 8 * GHID; i += 256) sx[i] = h[(size_t)base * GHID + i];
    __syncthreads();
    int ln = threadIdx.x >> 5, ch = threadIdx.x & 31;
    float al = 0.f, ar = 0.f;
    #pragma unroll
    for (int k = 0; k < GHID; ++k) {
        float xv = sx[ln * GHID + k];
        al = fmaf(xv, sWl[k * GOUT + ch], al);
        ar = fmaf(xv, sWr[k * GOUT + ch], ar);
    }
    xlh[(size_t)(base + ln) * GOUT + ch] = f2b(al);
    xr[(size_t)(base + ln) * GOUT + ch] = ar;
}

// ------- layer 1: 2 lanes/edge (8ch), 32 edges in flight (HID=16) -------
__global__ __launch_bounds__(256) void gl_L1(const int* __restrict__ rp,
        const int2* __restrict__ pse, const float* __restrict__ sea,
        const unsigned short* __restrict__ xlh, const float* __restrict__ xr,
        const float* __restrict__ We, const float* __restrict__ att,
        const float* __restrict__ b1, float* __restrict__ esc,
        float* __restrict__ lg, float* __restrict__ h1) {
    int u = blockIdx.x * 4 + (threadIdx.x >> 6);
    int lane = threadIdx.x & 63, sg = lane >> 1, ln2 = lane & 1;
    int beg = rp[u], end = rp[u + 1];
    float we[8], at[8], xru[8];
    #pragma unroll
    for (int q = 0; q < 8; ++q) {
        we[q] = We[ln2 * 8 + q];
        at[q] = att[ln2 * 8 + q];
        xru[q] = xr[(size_t)u * GHID + ln2 * 8 + q];
    }
    float mx = -3.0e38f, pd = 0.f;
    float acc[8] = {0, 0, 0, 0, 0, 0, 0, 0};
    int i = beg + sg;
    int2 p = (i < end) ? pse[i] : make_int2(0, 0);
    uint4 h = (i < end) ? *(const uint4*)(xlh + (size_t)p.x * GHID + ln2 * 8)
                        : make_uint4(0, 0, 0, 0);
    for (; i < end; i += 32) {
        int inx = i + 32;
        int2 pn = (inx < end) ? pse[inx] : make_int2(0, 0);
        uint4 hn = (inx < end) ? *(const uint4*)(xlh + (size_t)pn.x * GHID + ln2 * 8)
                               : make_uint4(0, 0, 0, 0);
        float xs[8];
        float s = dot8(h, xru, we, at, __int_as_float(p.y), xs);
        s += __shfl_xor(s, 1);
        if (ln2 == 0) lg[i] = s;
        float nm = fmaxf(mx, s);
        float sc = __expf(mx - nm), pp = __expf(s - nm);
        pd = pd * sc + pp;
        #pragma unroll
        for (int q = 0; q < 8; ++q) acc[q] = acc[q] * sc + pp * xs[q];
        mx = nm;
        p = pn; h = hn;
    }
    float lgself = 0.f;
    if (sg == 0) {
        uint4 hs = *(const uint4*)(xlh + (size_t)u * GHID + ln2 * 8);
        float xs[8];
        float s = dot8(hs, xru, we, at, sea[0] * (1.f / (float)GE), xs);
        s += __shfl_xor(s, 1);
        lgself = s;
        float nm = fmaxf(mx, s);
        float sc = __expf(mx - nm), pp = __expf(s - nm);
        pd = pd * sc + pp;
        #pragma unroll
        for (int q = 0; q < 8; ++q) acc[q] = acc[q] * sc + pp * xs[q];
        mx = nm;
    }
    #pragma unroll
    for (int o = 2; o <= 32; o <<= 1) {
        float mo = __shfl_xor(mx, o), po = __shfl_xor(pd, o);
        float ao[8];
        #pragma unroll
        for (int q = 0; q < 8; ++q) ao[q] = __shfl_xor(acc[q], o);
        float nm = fmaxf(mx, mo);
        float sa = __expf(mx - nm), sb = __expf(mo - nm);
        pd = pd * sa + po * sb;
        #pragma unroll
        for (int q = 0; q < 8; ++q) acc[q] = acc[q] * sa + ao[q] * sb;
        mx = nm;
    }
    float dinv = 1.f / pd;
    __threadfence_block();
    for (int j = beg + lane; j < end; j += 64)
        esc[j] = __expf(lg[j] - mx) * dinv;
    if (lane == 0) esc[GE + u] = __expf(lgself - mx) * dinv;
    if (lane < 2) {
        float o[8];
        #pragma unroll
        for (int q = 0; q < 8; ++q) {
            o[q] = acc[q] * dinv + b1[lane * 8 + q];
            o[q] = o[q] > 0.f ? o[q] : 0.f;
        }
        *(float4*)(h1 + (size_t)u * GHID + lane * 8)     = make_float4(o[0], o[1], o[2], o[3]);
        *(float4*)(h1 + (size_t)u * GHID + lane * 8 + 4) = make_float4(o[4], o[5], o[6], o[7]);
    }
}

// L2 body (device function): 4 lanes/edge (8ch), 16 edges in flight (OUT=32)
DEVFN void l2_body(int u, int tid, const int* __restrict__ rp,
        const int2* __restrict__ pse, const unsigned short* __restrict__ xlh,
        const float* __restrict__ xr, const float* __restrict__ We,
        const float* __restrict__ att, const float* __restrict__ b2,
        float* __restrict__ esc, float* __restrict__ lg, float* __restrict__ out0) {
    int lane = tid & 63, sg = lane >> 2, ln4 = lane & 3;
    int beg = rp[u], end = rp[u + 1];
    float we[8], at[8], xru[8];
    #pragma unroll
    for (int q = 0; q < 8; ++q) {
        we[q] = We[ln4 * 8 + q];
        at[q] = att[ln4 * 8 + q];
        xru[q] = xr[(size_t)u * GOUT + ln4 * 8 + q];
    }
    float mx = -3.0e38f, pd = 0.f;
    float acc[8] = {0, 0, 0, 0, 0, 0, 0, 0};
    int i = beg + sg;
    int2 p = (i < end) ? pse[i] : make_int2(0, 0);
    float ea = (i < end) ? esc[i] : 0.f;
    uint4 h = (i < end) ? *(const uint4*)(xlh + (size_t)p.x * GOUT + ln4 * 8)
                        : make_uint4(0, 0, 0, 0);
    for (; i < end; i += 16) {
        int inx = i + 16;
        int2 pn = (inx < end) ? pse[inx] : make_int2(0, 0);
        float ean = (inx < end) ? esc[inx] : 0.f;
        uint4 hn = (inx < end) ? *(const uint4*)(xlh + (size_t)pn.x * GOUT + ln4 * 8)
                               : make_uint4(0, 0, 0, 0);
        float xs[8];
        float s = dot8(h, xru, we, at, ea, xs);
        s += __shfl_xor(s, 1); s += __shfl_xor(s, 2);
        if (ln4 == 0) lg[i] = s;
        float nm = fmaxf(mx, s);
        float sc = __expf(mx - nm), pp = __expf(s - nm);
        pd = pd * sc + pp;
        #pragma unroll
        for (int q = 0; q < 8; ++q) acc[q] = acc[q] * sc + pp * xs[q];
        mx = nm;
        p = pn; ea = ean; h = hn;
    }
    float lgs = 0.f;
    if (sg < 2) {
        float eas = (sg == 0) ? esc[GE + u] : GEA2;
        uint4 hs = *(const uint4*)(xlh + (size_t)u * GOUT + ln4 * 8);
        float xs[8];
        float s = dot8(hs, xru, we, at, eas, xs);
        s += __shfl_xor(s, 1); s += __shfl_xor(s, 2);
        lgs = s;
        float nm = fmaxf(mx, s);
        float sc = __expf(mx - nm), pp = __expf(s - nm);
        pd = pd * sc + pp;
        #pragma unroll
        for (int q = 0; q < 8; ++q) acc[q] = acc[q] * sc + pp * xs[q];
        mx = nm;
    }
    #pragma unroll
    for (int o = 4; o <= 32; o <<= 1) {
        float mo = __shfl_xor(mx, o), po = __shfl_xor(pd, o);
        float ao[8];
        #pragma unroll
        for (int q = 0; q < 8; ++q) ao[q] = __shfl_xor(acc[q], o);
        float nm = fmaxf(mx, mo);
        float sa = __expf(mx - nm), sb = __expf(mo - nm);
        pd = pd * sa + po * sb;
        #pragma unroll
        for (int q = 0; q < 8; ++q) acc[q] = acc[q] * sa + ao[q] * sb;
        mx = nm;
    }
    float dinv = 1.f / pd;
    __threadfence_block();
    for (int j = beg + lane; j < end; j += 64)
        esc[j] = __expf(lg[j] - mx) * dinv;
    if (lane == 0) esc[GE + u]  = __expf(lgs - mx) * dinv;
    if (lane == 4) esc[GE1 + u] = __expf(lgs - mx) * dinv;
    if (lane < 4) {
        float o[8];
        #pragma unroll
        for (int q = 0; q < 8; ++q) o[q] = acc[q] * dinv + b2[lane * 8 + q];
        *(float4*)(out0 + (size_t)u * GOUT + lane * 8)     = make_float4(o[0], o[1], o[2], o[3]);
        *(float4*)(out0 + (size_t)u * GOUT + lane * 8 + 4) = make_float4(o[4], o[5], o[6], o[7]);
    }
}

// small-ws path: plain L2
__global__ __launch_bounds__(256) void gl_L2(const int* __restrict__ rp,
        const int2* __restrict__ pse, const unsigned short* __restrict__ xlh,
        const float* __restrict__ xr, const float* __restrict__ We,
        const float* __restrict__ att, const float* __restrict__ b2,
        float* __restrict__ esc, float* __restrict__ lg, float* __restrict__ out0) {
    int u = blockIdx.x * 4 + (threadIdx.x >> 6);
    l2_body(u, threadIdx.x, rp, pse, xlh, xr, We, att, b2, esc, lg, out0);
}

// big-ws path: interleaved [ei2-writer | L2]; pse lives in ws so ei2 region is free
__global__ __launch_bounds__(256) void gl_L2big(const int* __restrict__ rp,
        const int2* __restrict__ pse, const unsigned short* __restrict__ xlh,
        const float* __restrict__ xr, const float* __restrict__ We,
        const float* __restrict__ att, const float* __restrict__ b2,
        float* __restrict__ esc, float* __restrict__ lg, float* __restrict__ out0,
        const int* __restrict__ ei, const int* __restrict__ wpip,
        float* __restrict__ outb) {
    int b = blockIdx.x;
    int r = b % 3, q = b / 3;
    if (r == 0) {                                   // ei2 writer (independent of L2)
        int c = q * 256 + threadIdx.x;
        if (c >= GE2) return;
        int wpi = *wpip;
        int s, dd;
        if (c < GE)       { s = gidx(ei, c, wpi); dd = gidx(ei, (long long)GE + c, wpi); }
        else if (c < GE1) { s = dd = c - GE; }
        else              { s = dd = c - GE1; }
        outb[G0 + c]       = (float)s;
        outb[G0 + GE2 + c] = (float)dd;
        return;
    }
    int li = q * 2 + (r - 1);                       // L2 block index
    if (li >= NB_L2) return;
    int u = li * 4 + (threadIdx.x >> 6);
    l2_body(u, threadIdx.x, rp, pse, xlh, xr, We, att, b2, esc, lg, out0);
}

// full epilogue (small path): ei2 + a2
__global__ void gl_ep(const int* __restrict__ ei, const int* __restrict__ wpip,
                      const int* __restrict__ inv, const float* __restrict__ esc,
                      float* __restrict__ outb) {
    int c = blockIdx.x * blockDim.x + threadIdx.x;
    if (c >= GE2) return;
    int wpi = *wpip;
    int s, dd;
    float av;
    if (c < GE) {
        s = gidx(ei, c, wpi);
        dd = gidx(ei, (long long)GE + c, wpi);
        av = esc[inv[c]];
    } else if (c < GE1) {
        s = dd = c - GE;
        av = esc[c];
    } else {
        s = dd = c - GE1;
        av = esc[c];
    }
    outb[G0 + c]       = (float)s;
    outb[G0 + GE2 + c] = (float)dd;
    outb[G1 + c]       = av;
}

// a2-only epilogue (big path); inv[c] read then overwritten by a2[c]
__global__ void gl_ep_a2(const int* __restrict__ inv, const float* __restrict__ esc,
                         float* __restrict__ outb) {
    int c = blockIdx.x * blockDim.x + threadIdx.x;
    if (c >= GE2) return;
    float av = (c < GE) ? esc[inv[c]] : esc[c];
    outb[G1 + c] = av;
}

extern "C" void kernel_launch(void* const* d_in, const int* in_sizes, int n_in,
                              void* d_out, int out_size, void* d_ws, size_t ws_size,
                              hipStream_t stream) {
    const float* x     = (const float*)d_in[0];
    const int*   ei    = (const int*)d_in[1];
    const float* eattr = (const float*)d_in[2];
    const float* W1l   = (const float*)d_in[3];
    const float* W1r   = (const float*)d_in[4];
    const float* W1e   = (const float*)d_in[5];
    const float* att1  = (const float*)d_in[6];
    const float* b1    = (const float*)d_in[7];
    const float* W2l   = (const float*)d_in[8];
    const float* W2r   = (const float*)d_in[9];
    const float* W2e   = (const float*)d_in[10];
    const float* att2  = (const float*)d_in[11];
    const float* b2    = (const float*)d_in[12];
    float* outf = (float*)d_out;

    float* ws = (float*)d_ws;
    if (W_END * sizeof(float) > ws_size) {          // 56.8 MB minimum
        gl_sentinel<<<1, 64, 0, stream>>>(outf);
        return;
    }
    bool big = (W_ENDB * sizeof(float) <= ws_size); // 82.4 MB -> fused ei2 path

    float*          esc  = ws + W_ESC;
    float*          lg   = ws + W_LG;
    unsigned short* xl1h = (unsigned short*)(ws + W_XL1H);
    float*          xr1  = ws + W_XR1;
    unsigned short* xl2h = (unsigned short*)(ws + W_XL2H);
    float*          xr2  = ws + W_XR2;
    int*            rp   = (int*)(ws + W_RP);
    int*            cnt  = (int*)(ws + W_CNT);
    int*            bs   = (int*)(ws + W_BS);
    float*          sea  = ws + W_SEA;
    int*            wpi  = (int*)(ws + W_WPI);

    int*   rank = (int*)(outf + G0);                // dead after gl_slots
    int2*  pse  = big ? (int2*)(ws + W_PSE) : (int2*)(outf + G0);
    int*   inv  = (int*)(outf + G1);                // read-then-overwritten by a2
    float* h1   = outf;                             // chunk0, killed by L2's out0

    hipMemsetAsync(cnt, 0, GN * sizeof(int), stream);
    hipMemsetAsync(sea, 0, 2 * sizeof(float), stream);

    gl_detect<<<1, 64, 0, stream>>>(ei, wpi);
    gl_front<<<NB_MIX + NB_SUM, 256, 0, stream>>>(
        ei, wpi, cnt, rank, x, W1l, W1r, xl1h, xr1, eattr, sea);

    int nbe = (GE + 255) / 256;
    gl_scan1<<<(GN + 1023) / 1024, 1024, 0, stream>>>(cnt, rp, bs);
    gl_scan2<<<1, 128, 0, stream>>>(bs, (GN + 1023) / 1024);
    gl_scan3<<<(GN + 255) / 256, 256, 0, stream>>>(rp, bs);
    gl_slots<<<nbe, 256, 0, stream>>>(ei, wpi, rank, rp, inv);
    gl_scatter<<<8192, 256, 0, stream>>>(ei, wpi, eattr, inv, pse);

    gl_L1<<<GN / 4, 256, 0, stream>>>(rp, pse, sea, xl1h, xr1, W1e, att1, b1, esc, lg, h1);
    gl_projB<<<GN / 8, 256, 0, stream>>>(h1, W2l, W2r, xl2h, xr2);
    if (big) {
        gl_L2big<<<NB_L2BIG, 256, 0, stream>>>(rp, pse, xl2h, xr2, W2e, att2, b2,
                                               esc, lg, outf, ei, wpi, outf);
        gl_ep_a2<<<(GE2 + 255) / 256, 256, 0, stream>>>(inv, esc, outf);
    } else {
        gl_L2<<<GN / 4, 256, 0, stream>>>(rp, pse, xl2h, xr2, W2e, att2, b2, esc, lg, outf);
        gl_ep<<<(GE2 + 255) / 256, 256, 0, stream>>>(ei, wpi, inv, esc, outf);
    }
}